// Round 6
// baseline (2374.455 us; speedup 1.0000x reference)
//
#include <hip/hip_runtime.h>
#include <math.h>

#define KK 20
#define INVN (1.0 / 1310720.0)   // 1 / (B*N*K)
#define INVK (1.0f / 20.0f)

typedef unsigned char uchar;
typedef unsigned int uint;

// BN scale/shift from accumulated double sums
__device__ inline void bn_make(const double* __restrict__ st, int C,
                               const float* __restrict__ g, const float* __restrict__ be,
                               float* scl, float* shl, int c){
  const double m = st[c]*INVN, v = st[C+c]*INVN - m*m;
  const float s = (float)((double)g[c] / sqrt(v + 1e-5));
  scl[c] = s; shl[c] = be[c] - (float)m*s;
}

// rank phase shared by both KNN kernels (stable top_k semantics)
__device__ inline void rank_rows(const float (*D)[132], int t, int b, int n0,
                                 uchar* __restrict__ idx_out){
  const int rhalf = t >> 7;
  const int j = t & 127;
  for (int rep = 0; rep < 32; ++rep){
    const int rr = rep*2 + rhalf;
    const float* Drow = D[rr];
    const float myd = Drow[j];
    int cnt = 0;
    #pragma unroll 8
    for (int q4 = 0; q4 < 32; ++q4){
      const float4 v = *(const float4*)&Drow[q4*4];
      const int j0 = q4*4;
      cnt += (v.x < myd) + ((v.x == myd) & (j0     < j));
      cnt += (v.y < myd) + ((v.y == myd) & (j0 + 1 < j));
      cnt += (v.z < myd) + ((v.z == myd) & (j0 + 2 < j));
      cnt += (v.w < myd) + ((v.w == myd) & (j0 + 3 < j));
    }
    if (cnt < KK) idx_out[((size_t)b*128 + n0 + rr)*KK + cnt] = (uchar)j;
  }
}

// ---------------- KNN on 2-D points ----------------
__global__ __launch_bounds__(256) void knn1_kernel(const float* __restrict__ pts,
                                                   uchar* __restrict__ idx_out){
  const int b = blockIdx.x, t = threadIdx.x;
  __shared__ float px[128], py[128], sq[128];
  __shared__ float D[64][132];
  const float* p = pts + (size_t)b * 256;
  { float v = p[t]; if (t & 1) py[t>>1] = v; else px[t>>1] = v; }
  __syncthreads();
  if (t < 128) sq[t] = px[t]*px[t] + py[t]*py[t];
  __syncthreads();
  const int r = t >> 2, cg = t & 3;
  for (int half = 0; half < 2; ++half){
    const int n = half*64 + r;
    const float xn = px[n], yn = py[n], sn = sq[n];
    for (int jj = 0; jj < 32; ++jj){
      const int j = cg + jj*4;
      float d = sn + sq[j] - 2.0f*(xn*px[j] + yn*py[j]);
      if (j == n) d = 3.0e38f;
      D[r][j] = d;
    }
    __syncthreads();
    rank_rows(D, t, b, half*64, idx_out);
    __syncthreads();
  }
}

// ---------------- KNN on 32-D features ----------------
__global__ __launch_bounds__(256) void knn2_kernel(const float* __restrict__ x1,
                                                   uchar* __restrict__ idx_out){
  const int b = blockIdx.x, t = threadIdx.x;
  __shared__ float xs[128][36];
  __shared__ float sq[128];
  __shared__ float D[64][132];
  const float* xb = x1 + (size_t)b * 4096;
  for (int i4 = t; i4 < 1024; i4 += 256){
    const float4 v = *(const float4*)&xb[i4*4];
    *(float4*)&xs[i4>>3][(i4&7)*4] = v;
  }
  __syncthreads();
  if (t < 128){
    float s = 0.f;
    #pragma unroll
    for (int c = 0; c < 32; ++c){ const float v = xs[t][c]; s = fmaf(v, v, s); }
    sq[t] = s;
  }
  __syncthreads();
  const int r = t >> 2, cg = t & 3;
  for (int half = 0; half < 2; ++half){
    const int n = half*64 + r;
    float xt[32];
    #pragma unroll
    for (int c4 = 0; c4 < 8; ++c4){
      const float4 v = *(const float4*)&xs[n][c4*4];
      xt[c4*4+0]=v.x; xt[c4*4+1]=v.y; xt[c4*4+2]=v.z; xt[c4*4+3]=v.w;
    }
    const float sn = sq[n];
    for (int jj = 0; jj < 32; ++jj){
      const int j = cg + jj*4;
      float dot = 0.f;
      #pragma unroll
      for (int c4 = 0; c4 < 8; ++c4){
        const float4 v = *(const float4*)&xs[j][c4*4];
        dot = fmaf(xt[c4*4+0], v.x, dot);
        dot = fmaf(xt[c4*4+1], v.y, dot);
        dot = fmaf(xt[c4*4+2], v.z, dot);
        dot = fmaf(xt[c4*4+3], v.w, dot);
      }
      float d = sn + sq[j] - 2.0f*dot;
      if (j == n) d = 3.0e38f;
      D[r][j] = d;
    }
    __syncthreads();
    rank_rows(D, t, b, half*64, idx_out);
    __syncthreads();
  }
}

// ---------------- EC1 layer-1 stats via separability: h1(i,j)=p_i+q_j ----------------
__global__ __launch_bounds__(256) void pqs1(const float* __restrict__ feat,
    const uchar* __restrict__ idx, const float* __restrict__ W1, const float* __restrict__ B1,
    double* __restrict__ stat){
  const int t = threadIdx.x, b = blockIdx.x;
  __shared__ float Xl[128*20];
  __shared__ float W1l[32*36];
  __shared__ float Qp[128*36];
  __shared__ float ssum[32], ssq[32];
  __shared__ uint idxl[640];
  const float* fb = feat + (size_t)b*2048;
  for (int i4 = t; i4 < 512; i4 += 256){
    const float4 v = *(const float4*)&fb[i4*4];
    *(float4*)&Xl[(i4>>2)*20 + (i4&3)*4] = v;
  }
  { const float4 v = *(const float4*)&W1[t*4];
    *(float4*)&W1l[(t>>3)*36 + (t&7)*4] = v; }
  const uint* ig = (const uint*)(idx + (size_t)b*2560);
  for (int i = t; i < 640; i += 256) idxl[i] = ig[i];
  if (t < 32){ ssum[t]=0.f; ssq[t]=0.f; }
  __syncthreads();
  const int p = t & 127;
  const int c0 = __builtin_amdgcn_readfirstlane((t>>7)*16);
  float xi[16];
  #pragma unroll
  for (int c4 = 0; c4 < 4; ++c4){
    const float4 v = *(const float4*)&Xl[p*20 + c4*4];
    xi[c4*4]=v.x; xi[c4*4+1]=v.y; xi[c4*4+2]=v.z; xi[c4*4+3]=v.w;
  }
  float t1[16], qv[16];
  #pragma unroll
  for (int c = 0; c < 16; ++c){ t1[c]=0.f; qv[c]=0.f; }
  #pragma unroll
  for (int i = 0; i < 16; ++i){
    const float v = xi[i];
    #pragma unroll
    for (int c4 = 0; c4 < 4; ++c4){
      const float4 wa = *(const float4*)&W1l[i*36 + c0 + c4*4];
      const float4 wb = *(const float4*)&W1l[(16+i)*36 + c0 + c4*4];
      t1[c4*4+0]=fmaf(v,wa.x,t1[c4*4+0]); t1[c4*4+1]=fmaf(v,wa.y,t1[c4*4+1]);
      t1[c4*4+2]=fmaf(v,wa.z,t1[c4*4+2]); t1[c4*4+3]=fmaf(v,wa.w,t1[c4*4+3]);
      qv[c4*4+0]=fmaf(v,wb.x,qv[c4*4+0]); qv[c4*4+1]=fmaf(v,wb.y,qv[c4*4+1]);
      qv[c4*4+2]=fmaf(v,wb.z,qv[c4*4+2]); qv[c4*4+3]=fmaf(v,wb.w,qv[c4*4+3]);
    }
  }
  float pv[16];
  #pragma unroll
  for (int c = 0; c < 16; ++c){
    pv[c] = t1[c] - qv[c] + B1[c0+c];
    Qp[p*36 + c0 + c] = qv[c];
  }
  __syncthreads();
  const uchar* mi = (const uchar*)idxl + p*20;
  float Qs[16], Q2[16];
  #pragma unroll
  for (int c = 0; c < 16; ++c){ Qs[c]=0.f; Q2[c]=0.f; }
  for (int k = 0; k < KK; ++k){
    const int j = (int)mi[k] * 36;
    #pragma unroll
    for (int c4 = 0; c4 < 4; ++c4){
      const float4 q = *(const float4*)&Qp[j + c0 + c4*4];
      Qs[c4*4+0]+=q.x; Q2[c4*4+0]=fmaf(q.x,q.x,Q2[c4*4+0]);
      Qs[c4*4+1]+=q.y; Q2[c4*4+1]=fmaf(q.y,q.y,Q2[c4*4+1]);
      Qs[c4*4+2]+=q.z; Q2[c4*4+2]=fmaf(q.z,q.z,Q2[c4*4+2]);
      Qs[c4*4+3]+=q.w; Q2[c4*4+3]=fmaf(q.w,q.w,Q2[c4*4+3]);
    }
  }
  #pragma unroll
  for (int c = 0; c < 16; ++c){
    float a = fmaf(20.f, pv[c], Qs[c]);
    float q = fmaf(20.f*pv[c], pv[c], fmaf(2.f*pv[c], Qs[c], Q2[c]));
    #pragma unroll
    for (int m = 32; m; m >>= 1){ a += __shfl_xor(a,m,64); q += __shfl_xor(q,m,64); }
    if ((t & 63) == 0){ atomicAdd(&ssum[c0+c], a); atomicAdd(&ssq[c0+c], q); }
  }
  __syncthreads();
  if (t < 32){
    unsafeAtomicAdd(&stat[t], (double)ssum[t]);
    unsafeAtomicAdd(&stat[32+t], (double)ssq[t]);
  }
}

// ---------------- EC1 h2 stats: thread=(point,khalf), 32 outputs, 1-edge inner ----------------
__global__ __launch_bounds__(256) void ec1_s2(const float* __restrict__ feat,
    const uchar* __restrict__ idx, const float* __restrict__ W1, const float* __restrict__ B1,
    const double* __restrict__ st1, const float* __restrict__ g1, const float* __restrict__ be1,
    const float* __restrict__ W2, const float* __restrict__ B2,
    double* __restrict__ stat){
  const int t = threadIdx.x, b = blockIdx.x;
  __shared__ float Xl[128*20];
  __shared__ float W1l[32*36];
  __shared__ float W2l[32*36];
  __shared__ float Qp[128*36];
  __shared__ float sc1l[32], sh1l[32];
  __shared__ float ssum[32], ssq[32];
  __shared__ uint idxl[640];
  const float* fb = feat + (size_t)b*2048;
  for (int i4 = t; i4 < 512; i4 += 256){
    const float4 v = *(const float4*)&fb[i4*4];
    *(float4*)&Xl[(i4>>2)*20 + (i4&3)*4] = v;
  }
  { const float4 v = *(const float4*)&W1[t*4];
    *(float4*)&W1l[(t>>3)*36 + (t&7)*4] = v; }
  { const float4 v = *(const float4*)&W2[t*4];
    *(float4*)&W2l[(t>>3)*36 + (t&7)*4] = v; }
  const uint* ig = (const uint*)(idx + (size_t)b*2560);
  for (int i = t; i < 640; i += 256) idxl[i] = ig[i];
  if (t < 32){ ssum[t]=0.f; ssq[t]=0.f; bn_make(st1,32,g1,be1,sc1l,sh1l,t); }
  __syncthreads();
  const int p = t & 127, kh = t >> 7;
  float pv[32];
  {
    float xi[16];
    #pragma unroll
    for (int c4 = 0; c4 < 4; ++c4){
      const float4 v = *(const float4*)&Xl[p*20 + c4*4];
      xi[c4*4]=v.x; xi[c4*4+1]=v.y; xi[c4*4+2]=v.z; xi[c4*4+3]=v.w;
    }
    float t1[32], qv[32];
    #pragma unroll
    for (int c = 0; c < 32; ++c){ t1[c]=0.f; qv[c]=0.f; }
    #pragma unroll
    for (int i = 0; i < 16; ++i){
      const float v = xi[i];
      #pragma unroll
      for (int c4 = 0; c4 < 8; ++c4){
        const float4 wa = *(const float4*)&W1l[i*36 + c4*4];
        const float4 wb = *(const float4*)&W1l[(16+i)*36 + c4*4];
        t1[c4*4+0]=fmaf(v,wa.x,t1[c4*4+0]); t1[c4*4+1]=fmaf(v,wa.y,t1[c4*4+1]);
        t1[c4*4+2]=fmaf(v,wa.z,t1[c4*4+2]); t1[c4*4+3]=fmaf(v,wa.w,t1[c4*4+3]);
        qv[c4*4+0]=fmaf(v,wb.x,qv[c4*4+0]); qv[c4*4+1]=fmaf(v,wb.y,qv[c4*4+1]);
        qv[c4*4+2]=fmaf(v,wb.z,qv[c4*4+2]); qv[c4*4+3]=fmaf(v,wb.w,qv[c4*4+3]);
      }
    }
    #pragma unroll
    for (int c = 0; c < 32; ++c){
      const float sc = sc1l[c];
      pv[c] = fmaf(t1[c] - qv[c] + B1[c], sc, sh1l[c]);
      qv[c] *= sc;
    }
    if (kh == 0){
      const int sw = p & 7;
      #pragma unroll
      for (int cg = 0; cg < 8; ++cg){
        const int scg = cg ^ sw;
        *(float4*)&Qp[p*36 + (scg<<2)] =
          make_float4(qv[cg*4], qv[cg*4+1], qv[cg*4+2], qv[cg*4+3]);
      }
    }
  }
  __syncthreads();
  float ls[32], lq[32];
  #pragma unroll
  for (int c = 0; c < 32; ++c){ ls[c]=0.f; lq[c]=0.f; }
  const uchar* mi = (const uchar*)idxl + p*20;
  for (int e = 0; e < 10; ++e){
    const int j = mi[kh + e*2];
    const int jb = j*36, jsw = j & 7;
    float h2[32];
    #pragma unroll
    for (int c = 0; c < 32; ++c) h2[c] = B2[c];          // uniform -> sgpr
    #pragma unroll
    for (int i4 = 0; i4 < 8; ++i4){
      const float4 q = *(const float4*)&Qp[jb + ((i4 ^ jsw)<<2)];
      float rr[4];
      rr[0]=fmaxf(pv[i4*4+0]+q.x,0.f); rr[1]=fmaxf(pv[i4*4+1]+q.y,0.f);
      rr[2]=fmaxf(pv[i4*4+2]+q.z,0.f); rr[3]=fmaxf(pv[i4*4+3]+q.w,0.f);
      #pragma unroll
      for (int u = 0; u < 4; ++u){
        const float r = rr[u];
        #pragma unroll
        for (int c4 = 0; c4 < 8; ++c4){
          const float4 w = *(const float4*)&W2l[(i4*4+u)*36 + c4*4];  // uniform broadcast
          h2[c4*4+0]=fmaf(r,w.x,h2[c4*4+0]); h2[c4*4+1]=fmaf(r,w.y,h2[c4*4+1]);
          h2[c4*4+2]=fmaf(r,w.z,h2[c4*4+2]); h2[c4*4+3]=fmaf(r,w.w,h2[c4*4+3]);
        }
      }
    }
    #pragma unroll
    for (int c = 0; c < 32; ++c){
      ls[c] += h2[c];
      lq[c] = fmaf(h2[c], h2[c], lq[c]);
    }
  }
  const int lane = t & 63;
  #pragma unroll
  for (int c = 0; c < 32; ++c){
    float a = ls[c], q = lq[c];
    #pragma unroll
    for (int m = 32; m; m >>= 1){ a += __shfl_xor(a,m,64); q += __shfl_xor(q,m,64); }
    if (lane == 0){ atomicAdd(&ssum[c], a); atomicAdd(&ssq[c], q); }
  }
  __syncthreads();
  if (t < 32){
    unsafeAtomicAdd(&stat[t], (double)ssum[t]);
    unsafeAtomicAdd(&stat[32+t], (double)ssq[t]);
  }
}

// ---------------- EC1 output: thread=(point,khalf), 32 outputs, mean_k, then W3 ----------------
__global__ __launch_bounds__(256) void ec1_m(const float* __restrict__ feat,
    const uchar* __restrict__ idx, const float* __restrict__ W1, const float* __restrict__ B1,
    const double* __restrict__ st1, const float* __restrict__ g1, const float* __restrict__ be1,
    const float* __restrict__ W2, const float* __restrict__ B2,
    const double* __restrict__ st2, const float* __restrict__ g2, const float* __restrict__ be2,
    const float* __restrict__ W3, const float* __restrict__ B3,
    float* __restrict__ x1){
  const int t = threadIdx.x, b = blockIdx.x;
  __shared__ float Xl[128*20];
  __shared__ float W1l[32*36];
  __shared__ float W2l[32*36];   // bn2-scale folded
  __shared__ float W3l[32*36];
  __shared__ float Qp[128*36];
  __shared__ float mlds[128*66]; // [p][kh*33 + c]
  __shared__ float sc1l[32], sh1l[32], sc2l[32], sh2l[32], b2l[32];
  __shared__ uint idxl[640];
  if (t < 32) bn_make(st1,32,g1,be1,sc1l,sh1l,t);
  else if (t < 64) bn_make(st2,32,g2,be2,sc2l,sh2l,t-32);
  __syncthreads();
  const float* fb = feat + (size_t)b*2048;
  for (int i4 = t; i4 < 512; i4 += 256){
    const float4 v = *(const float4*)&fb[i4*4];
    *(float4*)&Xl[(i4>>2)*20 + (i4&3)*4] = v;
  }
  { const float4 v = *(const float4*)&W1[t*4];
    *(float4*)&W1l[(t>>3)*36 + (t&7)*4] = v; }
  { const float4 v = *(const float4*)&W2[t*4];
    const int col = (t&7)*4;
    float4 w;
    w.x = v.x*sc2l[col]; w.y = v.y*sc2l[col+1]; w.z = v.z*sc2l[col+2]; w.w = v.w*sc2l[col+3];
    *(float4*)&W2l[(t>>3)*36 + col] = w; }
  { const float4 v = *(const float4*)&W3[t*4];
    *(float4*)&W3l[(t>>3)*36 + (t&7)*4] = v; }
  if (t < 32) b2l[t] = fmaf(B2[t], sc2l[t], sh2l[t]);
  const uint* ig = (const uint*)(idx + (size_t)b*2560);
  for (int i = t; i < 640; i += 256) idxl[i] = ig[i];
  __syncthreads();
  const int p = t & 127, kh = t >> 7;
  float pv[32];
  {
    float xi[16];
    #pragma unroll
    for (int c4 = 0; c4 < 4; ++c4){
      const float4 v = *(const float4*)&Xl[p*20 + c4*4];
      xi[c4*4]=v.x; xi[c4*4+1]=v.y; xi[c4*4+2]=v.z; xi[c4*4+3]=v.w;
    }
    float t1[32], qv[32];
    #pragma unroll
    for (int c = 0; c < 32; ++c){ t1[c]=0.f; qv[c]=0.f; }
    #pragma unroll
    for (int i = 0; i < 16; ++i){
      const float v = xi[i];
      #pragma unroll
      for (int c4 = 0; c4 < 8; ++c4){
        const float4 wa = *(const float4*)&W1l[i*36 + c4*4];
        const float4 wb = *(const float4*)&W1l[(16+i)*36 + c4*4];
        t1[c4*4+0]=fmaf(v,wa.x,t1[c4*4+0]); t1[c4*4+1]=fmaf(v,wa.y,t1[c4*4+1]);
        t1[c4*4+2]=fmaf(v,wa.z,t1[c4*4+2]); t1[c4*4+3]=fmaf(v,wa.w,t1[c4*4+3]);
        qv[c4*4+0]=fmaf(v,wb.x,qv[c4*4+0]); qv[c4*4+1]=fmaf(v,wb.y,qv[c4*4+1]);
        qv[c4*4+2]=fmaf(v,wb.z,qv[c4*4+2]); qv[c4*4+3]=fmaf(v,wb.w,qv[c4*4+3]);
      }
    }
    #pragma unroll
    for (int c = 0; c < 32; ++c){
      const float sc = sc1l[c];
      pv[c] = fmaf(t1[c] - qv[c] + B1[c], sc, sh1l[c]);
      qv[c] *= sc;
    }
    if (kh == 0){
      const int sw = p & 7;
      #pragma unroll
      for (int cg = 0; cg < 8; ++cg){
        const int scg = cg ^ sw;
        *(float4*)&Qp[p*36 + (scg<<2)] =
          make_float4(qv[cg*4], qv[cg*4+1], qv[cg*4+2], qv[cg*4+3]);
      }
    }
  }
  __syncthreads();
  float macc[32];
  #pragma unroll
  for (int c = 0; c < 32; ++c) macc[c] = 0.f;
  const uchar* mi = (const uchar*)idxl + p*20;
  for (int e = 0; e < 10; ++e){
    const int j = mi[kh + e*2];
    const int jb = j*36, jsw = j & 7;
    float h2[32];
    #pragma unroll
    for (int c4 = 0; c4 < 8; ++c4){
      const float4 bb = *(const float4*)&b2l[c4*4];
      h2[c4*4+0]=bb.x; h2[c4*4+1]=bb.y; h2[c4*4+2]=bb.z; h2[c4*4+3]=bb.w;
    }
    #pragma unroll
    for (int i4 = 0; i4 < 8; ++i4){
      const float4 q = *(const float4*)&Qp[jb + ((i4 ^ jsw)<<2)];
      float rr[4];
      rr[0]=fmaxf(pv[i4*4+0]+q.x,0.f); rr[1]=fmaxf(pv[i4*4+1]+q.y,0.f);
      rr[2]=fmaxf(pv[i4*4+2]+q.z,0.f); rr[3]=fmaxf(pv[i4*4+3]+q.w,0.f);
      #pragma unroll
      for (int u = 0; u < 4; ++u){
        const float r = rr[u];
        #pragma unroll
        for (int c4 = 0; c4 < 8; ++c4){
          const float4 w = *(const float4*)&W2l[(i4*4+u)*36 + c4*4];
          h2[c4*4+0]=fmaf(r,w.x,h2[c4*4+0]); h2[c4*4+1]=fmaf(r,w.y,h2[c4*4+1]);
          h2[c4*4+2]=fmaf(r,w.z,h2[c4*4+2]); h2[c4*4+3]=fmaf(r,w.w,h2[c4*4+3]);
        }
      }
    }
    #pragma unroll
    for (int c = 0; c < 32; ++c) macc[c] += fmaxf(h2[c], 0.f);
  }
  #pragma unroll
  for (int c = 0; c < 32; ++c) mlds[p*66 + kh*33 + c] = macc[c] * INVK;
  __syncthreads();
  // W3 phase: thread -> (point, 16-col group); W3 from LDS uniform broadcast
  const int pt = t & 127;
  const int og = __builtin_amdgcn_readfirstlane((t>>7)*16);
  float o16[16];
  #pragma unroll
  for (int c = 0; c < 16; ++c) o16[c] = B3[og + c];
  #pragma unroll
  for (int i = 0; i < 32; ++i){
    const float v = mlds[pt*66 + i] + mlds[pt*66 + 33 + i];
    #pragma unroll
    for (int c4 = 0; c4 < 4; ++c4){
      const float4 w = *(const float4*)&W3l[i*36 + og + c4*4];
      o16[c4*4+0]=fmaf(v,w.x,o16[c4*4+0]); o16[c4*4+1]=fmaf(v,w.y,o16[c4*4+1]);
      o16[c4*4+2]=fmaf(v,w.z,o16[c4*4+2]); o16[c4*4+3]=fmaf(v,w.w,o16[c4*4+3]);
    }
  }
  float* o = x1 + ((size_t)b*128 + pt)*32 + og;
  #pragma unroll
  for (int c4 = 0; c4 < 4; ++c4)
    *(float4*)&o[c4*4] = make_float4(o16[c4*4], o16[c4*4+1], o16[c4*4+2], o16[c4*4+3]);
}

// ---------------- EC2 h4 stats via separability ----------------
__global__ __launch_bounds__(256) void pqs4(const float* __restrict__ x1,
    const uchar* __restrict__ idx, const float* __restrict__ W4, const float* __restrict__ B4,
    double* __restrict__ stat){
  const int t = threadIdx.x, b = blockIdx.x;
  __shared__ float X1b[128*33];
  __shared__ float W4l[64*68];
  __shared__ float Qp4[128*68];
  __shared__ float ssum[64], ssq[64];
  __shared__ uint idxl[640];
  const float* xb = x1 + (size_t)b*4096;
  for (int i4 = t; i4 < 1024; i4 += 256){
    const float4 v = *(const float4*)&xb[i4*4];
    const int r = i4>>3, c = (i4&7)*4;
    X1b[r*33+c]=v.x; X1b[r*33+c+1]=v.y; X1b[r*33+c+2]=v.z; X1b[r*33+c+3]=v.w;
  }
  for (int i4 = t; i4 < 1024; i4 += 256){
    const float4 v = *(const float4*)&W4[i4*4];
    *(float4*)&W4l[(i4>>4)*68 + (i4&15)*4] = v;
  }
  const uint* ig = (const uint*)(idx + (size_t)b*2560);
  for (int i = t; i < 640; i += 256) idxl[i] = ig[i];
  if (t < 64){ ssum[t]=0.f; ssq[t]=0.f; }
  __syncthreads();
  const int p = t & 127;
  const int c0 = __builtin_amdgcn_readfirstlane((t>>7)*32);
  float t1[32], qv[32];
  #pragma unroll
  for (int c = 0; c < 32; ++c){ t1[c]=0.f; qv[c]=0.f; }
  #pragma unroll
  for (int i = 0; i < 32; ++i){
    const float v = X1b[p*33 + i];
    #pragma unroll
    for (int c4 = 0; c4 < 8; ++c4){
      const float4 wa = *(const float4*)&W4l[i*68 + c0 + c4*4];
      const float4 wb = *(const float4*)&W4l[(32+i)*68 + c0 + c4*4];
      t1[c4*4+0]=fmaf(v,wa.x,t1[c4*4+0]); t1[c4*4+1]=fmaf(v,wa.y,t1[c4*4+1]);
      t1[c4*4+2]=fmaf(v,wa.z,t1[c4*4+2]); t1[c4*4+3]=fmaf(v,wa.w,t1[c4*4+3]);
      qv[c4*4+0]=fmaf(v,wb.x,qv[c4*4+0]); qv[c4*4+1]=fmaf(v,wb.y,qv[c4*4+1]);
      qv[c4*4+2]=fmaf(v,wb.z,qv[c4*4+2]); qv[c4*4+3]=fmaf(v,wb.w,qv[c4*4+3]);
    }
  }
  float pv[32];
  #pragma unroll
  for (int c = 0; c < 32; ++c){
    pv[c] = t1[c] - qv[c] + B4[c0+c];
    Qp4[p*68 + c0 + c] = qv[c];
  }
  __syncthreads();
  const uchar* mi = (const uchar*)idxl + p*20;
  float Qs[32], Q2[32];
  #pragma unroll
  for (int c = 0; c < 32; ++c){ Qs[c]=0.f; Q2[c]=0.f; }
  for (int k = 0; k < KK; ++k){
    const int j = (int)mi[k] * 68;
    #pragma unroll
    for (int c4 = 0; c4 < 8; ++c4){
      const float4 q = *(const float4*)&Qp4[j + c0 + c4*4];
      Qs[c4*4+0]+=q.x; Q2[c4*4+0]=fmaf(q.x,q.x,Q2[c4*4+0]);
      Qs[c4*4+1]+=q.y; Q2[c4*4+1]=fmaf(q.y,q.y,Q2[c4*4+1]);
      Qs[c4*4+2]+=q.z; Q2[c4*4+2]=fmaf(q.z,q.z,Q2[c4*4+2]);
      Qs[c4*4+3]+=q.w; Q2[c4*4+3]=fmaf(q.w,q.w,Q2[c4*4+3]);
    }
  }
  #pragma unroll
  for (int c = 0; c < 32; ++c){
    float a = fmaf(20.f, pv[c], Qs[c]);
    float q = fmaf(20.f*pv[c], pv[c], fmaf(2.f*pv[c], Qs[c], Q2[c]));
    #pragma unroll
    for (int m = 32; m; m >>= 1){ a += __shfl_xor(a,m,64); q += __shfl_xor(q,m,64); }
    if ((t & 63) == 0){ atomicAdd(&ssum[c0+c], a); atomicAdd(&ssq[c0+c], q); }
  }
  __syncthreads();
  if (t < 64){
    unsafeAtomicAdd(&stat[t], (double)ssum[t]);
    unsafeAtomicAdd(&stat[64+t], (double)ssq[t]);
  }
}

// ---------------- EC2 output: fully LDS-staged, QW buffer = W4l -> Qp4 -> W5l ----------------
__global__ __launch_bounds__(256) void ec2_m(const float* __restrict__ x1,
    const uchar* __restrict__ idx, const float* __restrict__ W4, const float* __restrict__ B4,
    const double* __restrict__ st4, const float* __restrict__ g4, const float* __restrict__ be4,
    const float* __restrict__ W5, const float* __restrict__ B5,
    float* __restrict__ x2){
  const int t = threadIdx.x, b = blockIdx.x;
  __shared__ float xm[128*68];   // X (stride 36) then mlds (stride 68)
  __shared__ float QW[128*68];   // W4l (stride 68) -> Qp4 -> W5l
  __shared__ float sc4l[64], sh4l[64];
  __shared__ uint idxl[640];
  if (t < 64) bn_make(st4, 64, g4, be4, sc4l, sh4l, t);
  const float* xb = x1 + (size_t)b*4096;
  for (int i4 = t; i4 < 1024; i4 += 256){
    const float4 v = *(const float4*)&xb[i4*4];
    *(float4*)&xm[(i4>>3)*36 + (i4&7)*4] = v;
  }
  for (int i4 = t; i4 < 1024; i4 += 256){
    const float4 v = *(const float4*)&W4[i4*4];
    *(float4*)&QW[(i4>>4)*68 + (i4&15)*4] = v;
  }
  const uint* ig = (const uint*)(idx + (size_t)b*2560);
  for (int i = t; i < 640; i += 256) idxl[i] = ig[i];
  __syncthreads();
  const int p = t & 127;
  const int c0 = __builtin_amdgcn_readfirstlane((t>>7)*32);
  float pv[32], qs[32];
  {
    float t1[32], qv[32];
    #pragma unroll
    for (int c = 0; c < 32; ++c){ t1[c]=0.f; qv[c]=0.f; }
    #pragma unroll
    for (int i = 0; i < 32; ++i){
      const float v = xm[p*36 + i];
      #pragma unroll
      for (int c4 = 0; c4 < 8; ++c4){
        const float4 wa = *(const float4*)&QW[i*68 + c0 + c4*4];
        const float4 wb = *(const float4*)&QW[(32+i)*68 + c0 + c4*4];
        t1[c4*4+0]=fmaf(v,wa.x,t1[c4*4+0]); t1[c4*4+1]=fmaf(v,wa.y,t1[c4*4+1]);
        t1[c4*4+2]=fmaf(v,wa.z,t1[c4*4+2]); t1[c4*4+3]=fmaf(v,wa.w,t1[c4*4+3]);
        qv[c4*4+0]=fmaf(v,wb.x,qv[c4*4+0]); qv[c4*4+1]=fmaf(v,wb.y,qv[c4*4+1]);
        qv[c4*4+2]=fmaf(v,wb.z,qv[c4*4+2]); qv[c4*4+3]=fmaf(v,wb.w,qv[c4*4+3]);
      }
    }
    #pragma unroll
    for (int c = 0; c < 32; ++c){
      const float sc = sc4l[c0+c];
      pv[c] = fmaf(t1[c] - qv[c] + B4[c0+c], sc, sh4l[c0+c]);
      qs[c] = qv[c]*sc;
    }
  }
  __syncthreads();   // all W4l reads done
  {
    const int sw = p & 7;
    #pragma unroll
    for (int cg = 0; cg < 8; ++cg){
      const int scg = cg ^ sw;
      *(float4*)&QW[p*68 + c0 + (scg<<2)] =
        make_float4(qs[cg*4], qs[cg*4+1], qs[cg*4+2], qs[cg*4+3]);
    }
  }
  __syncthreads();
  float macc[32];
  #pragma unroll
  for (int c = 0; c < 32; ++c) macc[c] = 0.f;
  const uchar* mi = (const uchar*)idxl + p*20;
  for (int k = 0; k < KK; ++k){
    const int j = mi[k];
    const int jb = j*68 + c0, jsw = j & 7;
    #pragma unroll
    for (int c4 = 0; c4 < 8; ++c4){
      const float4 q = *(const float4*)&QW[jb + ((c4 ^ jsw)<<2)];
      macc[c4*4+0] += fmaxf(pv[c4*4+0] + q.x, 0.f);
      macc[c4*4+1] += fmaxf(pv[c4*4+1] + q.y, 0.f);
      macc[c4*4+2] += fmaxf(pv[c4*4+2] + q.z, 0.f);
      macc[c4*4+3] += fmaxf(pv[c4*4+3] + q.w, 0.f);
    }
  }
  #pragma unroll
  for (int c4 = 0; c4 < 8; ++c4)
    *(float4*)&xm[p*68 + c0 + c4*4] =
      make_float4(macc[c4*4]*INVK, macc[c4*4+1]*INVK, macc[c4*4+2]*INVK, macc[c4*4+3]*INVK);
  __syncthreads();   // all Qp4 reads done
  for (int i4 = t; i4 < 1024; i4 += 256){
    const float4 v = *(const float4*)&W5[i4*4];
    *(float4*)&QW[(i4>>4)*68 + (i4&15)*4] = v;
  }
  __syncthreads();
  // W5 phase: thread -> (point, 32-col group); W5 from LDS uniform broadcast
  float o[32];
  #pragma unroll
  for (int c = 0; c < 32; ++c) o[c] = B5[c0 + c];
  #pragma unroll
  for (int i = 0; i < 64; ++i){
    const float v = xm[p*68 + i];
    #pragma unroll
    for (int c4 = 0; c4 < 8; ++c4){
      const float4 w = *(const float4*)&QW[i*68 + c0 + c4*4];
      o[c4*4+0]=fmaf(v,w.x,o[c4*4+0]); o[c4*4+1]=fmaf(v,w.y,o[c4*4+1]);
      o[c4*4+2]=fmaf(v,w.z,o[c4*4+2]); o[c4*4+3]=fmaf(v,w.w,o[c4*4+3]);
    }
  }
  float* ox = x2 + ((size_t)b*128 + p)*64 + c0;
  #pragma unroll
  for (int c4 = 0; c4 < 8; ++c4)
    *(float4*)&ox[c4*4] = make_float4(o[c4*4], o[c4*4+1], o[c4*4+2], o[c4*4+3]);
}

// ---------------- global max over N + head MLP ----------------
__global__ __launch_bounds__(128) void head_kernel(const float* __restrict__ x2,
    const float* __restrict__ w1, const float* __restrict__ b1,
    const float* __restrict__ w2, const float* __restrict__ b2,
    const float* __restrict__ w3, const float* __restrict__ b3,
    float* __restrict__ out){
  const int b = blockIdx.x, t = threadIdx.x;
  __shared__ float gmax2[128];
  __shared__ float h1s[128];
  __shared__ float part[2];
  {
    const int c = t & 63, nh = t >> 6;
    const float* xb = x2 + (size_t)b * 128 * 64 + (size_t)nh * 64 * 64 + c;
    float m = -3.0e38f;
    for (int n = 0; n < 64; ++n) m = fmaxf(m, xb[n*64]);
    gmax2[t] = m;
  }
  __syncthreads();
  float a = b1[t];
  #pragma unroll
  for (int i = 0; i < 64; ++i) a = fmaf(fmaxf(gmax2[i], gmax2[64+i]), w1[i*128 + t], a);
  h1s[t] = fmaxf(a, 0.f);
  __syncthreads();
  float h2 = b2[t];
  #pragma unroll
  for (int i = 0; i < 128; ++i) h2 = fmaf(h1s[i], w2[i*128 + t], h2);
  h2 = fmaxf(h2, 0.f);
  float pr = h2 * w3[t];
  #pragma unroll
  for (int m = 32; m; m >>= 1) pr += __shfl_xor(pr, m, 64);
  if ((t & 63) == 0) part[t >> 6] = pr;
  __syncthreads();
  if (t == 0) out[b] = part[0] + part[1] + b3[0];
}

extern "C" void kernel_launch(void* const* d_in, const int* in_sizes, int n_in,
                              void* d_out, int out_size, void* d_ws, size_t ws_size,
                              hipStream_t stream) {
  const float* points = (const float*)d_in[0];
  const float* feat   = (const float*)d_in[1];
  const float* c1_w1  = (const float*)d_in[2];
  const float* c1_b1  = (const float*)d_in[3];
  const float* c1_g1  = (const float*)d_in[4];
  const float* c1_be1 = (const float*)d_in[5];
  const float* c1_w2  = (const float*)d_in[6];
  const float* c1_b2  = (const float*)d_in[7];
  const float* c1_g2  = (const float*)d_in[8];
  const float* c1_be2 = (const float*)d_in[9];
  const float* c1_w3  = (const float*)d_in[10];
  const float* c1_b3  = (const float*)d_in[11];
  const float* c2_w1  = (const float*)d_in[12];
  const float* c2_b1  = (const float*)d_in[13];
  const float* c2_g1  = (const float*)d_in[14];
  const float* c2_be1 = (const float*)d_in[15];
  const float* c2_w2  = (const float*)d_in[16];
  const float* c2_b2  = (const float*)d_in[17];
  const float* m_w1   = (const float*)d_in[18];
  const float* m_b1   = (const float*)d_in[19];
  const float* m_w2   = (const float*)d_in[20];
  const float* m_b2   = (const float*)d_in[21];
  const float* m_w3   = (const float*)d_in[22];
  const float* m_b3   = (const float*)d_in[23];
  float* out = (float*)d_out;

  char* ws = (char*)d_ws;
  const size_t NEDGE = (size_t)512 * 128 * KK;
  uchar*  idx1 = (uchar*)ws;
  uchar*  idx2 = (uchar*)(ws + NEDGE);
  float*  x1   = (float*)(ws + 2*NEDGE);                       // 8.39 MB
  float*  x2   = (float*)(ws + 2*NEDGE + (size_t)65536*32*4);  // 16.8 MB
  double* stats = (double*)(ws + 2*NEDGE + (size_t)65536*96*4);
  double* st1 = stats;         // [sum32 | sq32]  (h1)
  double* st2 = stats + 64;    // [sum32 | sq32]  (h2)
  double* st4 = stats + 128;   // [sum64 | sq64]  (h4)

  hipMemsetAsync(stats, 0, 256*sizeof(double), stream);

  knn1_kernel<<<512, 256, 0, stream>>>(points, idx1);
  pqs1      <<<512, 256, 0, stream>>>(feat, idx1, c1_w1, c1_b1, st1);
  ec1_s2    <<<512, 256, 0, stream>>>(feat, idx1, c1_w1, c1_b1, st1, c1_g1, c1_be1,
                                      c1_w2, c1_b2, st2);
  ec1_m     <<<512, 256, 0, stream>>>(feat, idx1, c1_w1, c1_b1, st1, c1_g1, c1_be1,
                                      c1_w2, c1_b2, st2, c1_g2, c1_be2, c1_w3, c1_b3, x1);
  knn2_kernel<<<512, 256, 0, stream>>>(x1, idx2);
  pqs4      <<<512, 256, 0, stream>>>(x1, idx2, c2_w1, c2_b1, st4);
  ec2_m     <<<512, 256, 0, stream>>>(x1, idx2, c2_w1, c2_b1, st4, c2_g1, c2_be1,
                                      c2_w2, c2_b2, x2);
  head_kernel<<<512, 128, 0, stream>>>(x2, m_w1, m_b1, m_w2, m_b2, m_w3, m_b3, out);
}

// Round 7
// 1657.142 us; speedup vs baseline: 1.4329x; 1.4329x over previous
//
#include <hip/hip_runtime.h>
#include <math.h>

#define KK 20
#define INVN (1.0 / 1310720.0)   // 1 / (B*N*K)
#define INVK (1.0f / 20.0f)

typedef unsigned char uchar;
typedef unsigned int uint;

// BN scale/shift from accumulated double sums
__device__ inline void bn_make(const double* __restrict__ st, int C,
                               const float* __restrict__ g, const float* __restrict__ be,
                               float* scl, float* shl, int c){
  const double m = st[c]*INVN, v = st[C+c]*INVN - m*m;
  const float s = (float)((double)g[c] / sqrt(v + 1e-5));
  scl[c] = s; shl[c] = be[c] - (float)m*s;
}

// rank phase shared by both KNN kernels (stable top_k semantics)
__device__ inline void rank_rows(const float (*D)[132], int t, int b, int n0,
                                 uchar* __restrict__ idx_out){
  const int rhalf = t >> 7;
  const int j = t & 127;
  for (int rep = 0; rep < 32; ++rep){
    const int rr = rep*2 + rhalf;
    const float* Drow = D[rr];
    const float myd = Drow[j];
    int cnt = 0;
    #pragma unroll 8
    for (int q4 = 0; q4 < 32; ++q4){
      const float4 v = *(const float4*)&Drow[q4*4];
      const int j0 = q4*4;
      cnt += (v.x < myd) + ((v.x == myd) & (j0     < j));
      cnt += (v.y < myd) + ((v.y == myd) & (j0 + 1 < j));
      cnt += (v.z < myd) + ((v.z == myd) & (j0 + 2 < j));
      cnt += (v.w < myd) + ((v.w == myd) & (j0 + 3 < j));
    }
    if (cnt < KK) idx_out[((size_t)b*128 + n0 + rr)*KK + cnt] = (uchar)j;
  }
}

// ---------------- KNN on 2-D points ----------------
__global__ __launch_bounds__(256) void knn1_kernel(const float* __restrict__ pts,
                                                   uchar* __restrict__ idx_out){
  const int b = blockIdx.x, t = threadIdx.x;
  __shared__ float px[128], py[128], sq[128];
  __shared__ float D[64][132];
  const float* p = pts + (size_t)b * 256;
  { float v = p[t]; if (t & 1) py[t>>1] = v; else px[t>>1] = v; }
  __syncthreads();
  if (t < 128) sq[t] = px[t]*px[t] + py[t]*py[t];
  __syncthreads();
  const int r = t >> 2, cg = t & 3;
  for (int half = 0; half < 2; ++half){
    const int n = half*64 + r;
    const float xn = px[n], yn = py[n], sn = sq[n];
    for (int jj = 0; jj < 32; ++jj){
      const int j = cg + jj*4;
      float d = sn + sq[j] - 2.0f*(xn*px[j] + yn*py[j]);
      if (j == n) d = 3.0e38f;
      D[r][j] = d;
    }
    __syncthreads();
    rank_rows(D, t, b, half*64, idx_out);
    __syncthreads();
  }
}

// ---------------- KNN on 32-D features ----------------
__global__ __launch_bounds__(256) void knn2_kernel(const float* __restrict__ x1,
                                                   uchar* __restrict__ idx_out){
  const int b = blockIdx.x, t = threadIdx.x;
  __shared__ float xs[128][36];
  __shared__ float sq[128];
  __shared__ float D[64][132];
  const float* xb = x1 + (size_t)b * 4096;
  for (int i4 = t; i4 < 1024; i4 += 256){
    const float4 v = *(const float4*)&xb[i4*4];
    *(float4*)&xs[i4>>3][(i4&7)*4] = v;
  }
  __syncthreads();
  if (t < 128){
    float s = 0.f;
    #pragma unroll
    for (int c = 0; c < 32; ++c){ const float v = xs[t][c]; s = fmaf(v, v, s); }
    sq[t] = s;
  }
  __syncthreads();
  const int r = t >> 2, cg = t & 3;
  for (int half = 0; half < 2; ++half){
    const int n = half*64 + r;
    float xt[32];
    #pragma unroll
    for (int c4 = 0; c4 < 8; ++c4){
      const float4 v = *(const float4*)&xs[n][c4*4];
      xt[c4*4+0]=v.x; xt[c4*4+1]=v.y; xt[c4*4+2]=v.z; xt[c4*4+3]=v.w;
    }
    const float sn = sq[n];
    for (int jj = 0; jj < 32; ++jj){
      const int j = cg + jj*4;
      float dot = 0.f;
      #pragma unroll
      for (int c4 = 0; c4 < 8; ++c4){
        const float4 v = *(const float4*)&xs[j][c4*4];
        dot = fmaf(xt[c4*4+0], v.x, dot);
        dot = fmaf(xt[c4*4+1], v.y, dot);
        dot = fmaf(xt[c4*4+2], v.z, dot);
        dot = fmaf(xt[c4*4+3], v.w, dot);
      }
      float d = sn + sq[j] - 2.0f*dot;
      if (j == n) d = 3.0e38f;
      D[r][j] = d;
    }
    __syncthreads();
    rank_rows(D, t, b, half*64, idx_out);
    __syncthreads();
  }
}

// ---------------- EC1 layer-1 stats via separability: h1(i,j)=p_i+q_j ----------------
__global__ __launch_bounds__(256) void pqs1(const float* __restrict__ feat,
    const uchar* __restrict__ idx, const float* __restrict__ W1, const float* __restrict__ B1,
    double* __restrict__ stat){
  const int t = threadIdx.x, b = blockIdx.x;
  __shared__ float Xl[128*20];
  __shared__ float W1l[32*36];
  __shared__ float Qp[128*36];
  __shared__ float ssum[32], ssq[32];
  __shared__ uint idxl[640];
  const float* fb = feat + (size_t)b*2048;
  for (int i4 = t; i4 < 512; i4 += 256){
    const float4 v = *(const float4*)&fb[i4*4];
    *(float4*)&Xl[(i4>>2)*20 + (i4&3)*4] = v;
  }
  { const float4 v = *(const float4*)&W1[t*4];
    *(float4*)&W1l[(t>>3)*36 + (t&7)*4] = v; }
  const uint* ig = (const uint*)(idx + (size_t)b*2560);
  for (int i = t; i < 640; i += 256) idxl[i] = ig[i];
  if (t < 32){ ssum[t]=0.f; ssq[t]=0.f; }
  __syncthreads();
  const int p = t & 127;
  const int c0 = __builtin_amdgcn_readfirstlane((t>>7)*16);
  float xi[16];
  #pragma unroll
  for (int c4 = 0; c4 < 4; ++c4){
    const float4 v = *(const float4*)&Xl[p*20 + c4*4];
    xi[c4*4]=v.x; xi[c4*4+1]=v.y; xi[c4*4+2]=v.z; xi[c4*4+3]=v.w;
  }
  float t1[16], qv[16];
  #pragma unroll
  for (int c = 0; c < 16; ++c){ t1[c]=0.f; qv[c]=0.f; }
  #pragma unroll
  for (int i = 0; i < 16; ++i){
    const float v = xi[i];
    #pragma unroll
    for (int c4 = 0; c4 < 4; ++c4){
      const float4 wa = *(const float4*)&W1l[i*36 + c0 + c4*4];
      const float4 wb = *(const float4*)&W1l[(16+i)*36 + c0 + c4*4];
      t1[c4*4+0]=fmaf(v,wa.x,t1[c4*4+0]); t1[c4*4+1]=fmaf(v,wa.y,t1[c4*4+1]);
      t1[c4*4+2]=fmaf(v,wa.z,t1[c4*4+2]); t1[c4*4+3]=fmaf(v,wa.w,t1[c4*4+3]);
      qv[c4*4+0]=fmaf(v,wb.x,qv[c4*4+0]); qv[c4*4+1]=fmaf(v,wb.y,qv[c4*4+1]);
      qv[c4*4+2]=fmaf(v,wb.z,qv[c4*4+2]); qv[c4*4+3]=fmaf(v,wb.w,qv[c4*4+3]);
    }
  }
  float pv[16];
  #pragma unroll
  for (int c = 0; c < 16; ++c){
    pv[c] = t1[c] - qv[c] + B1[c0+c];
    Qp[p*36 + c0 + c] = qv[c];
  }
  __syncthreads();
  const uchar* mi = (const uchar*)idxl + p*20;
  float Qs[16], Q2[16];
  #pragma unroll
  for (int c = 0; c < 16; ++c){ Qs[c]=0.f; Q2[c]=0.f; }
  #pragma unroll 1
  for (int k = 0; k < KK; ++k){
    const int j = (int)mi[k] * 36;
    #pragma unroll
    for (int c4 = 0; c4 < 4; ++c4){
      const float4 q = *(const float4*)&Qp[j + c0 + c4*4];
      Qs[c4*4+0]+=q.x; Q2[c4*4+0]=fmaf(q.x,q.x,Q2[c4*4+0]);
      Qs[c4*4+1]+=q.y; Q2[c4*4+1]=fmaf(q.y,q.y,Q2[c4*4+1]);
      Qs[c4*4+2]+=q.z; Q2[c4*4+2]=fmaf(q.z,q.z,Q2[c4*4+2]);
      Qs[c4*4+3]+=q.w; Q2[c4*4+3]=fmaf(q.w,q.w,Q2[c4*4+3]);
    }
  }
  #pragma unroll
  for (int c = 0; c < 16; ++c){
    float a = fmaf(20.f, pv[c], Qs[c]);
    float q = fmaf(20.f*pv[c], pv[c], fmaf(2.f*pv[c], Qs[c], Q2[c]));
    #pragma unroll
    for (int m = 32; m; m >>= 1){ a += __shfl_xor(a,m,64); q += __shfl_xor(q,m,64); }
    if ((t & 63) == 0){ atomicAdd(&ssum[c0+c], a); atomicAdd(&ssq[c0+c], q); }
  }
  __syncthreads();
  if (t < 32){
    unsafeAtomicAdd(&stat[t], (double)ssum[t]);
    unsafeAtomicAdd(&stat[32+t], (double)ssq[t]);
  }
}

// ---------------- EC1 h2 stats: thread=(point, ch-half), 16 outputs, all 20 edges ----------------
__global__ __launch_bounds__(256) void ec1_s2(const float* __restrict__ feat,
    const uchar* __restrict__ idx, const float* __restrict__ W1, const float* __restrict__ B1,
    const double* __restrict__ st1, const float* __restrict__ g1, const float* __restrict__ be1,
    const float* __restrict__ W2, const float* __restrict__ B2,
    double* __restrict__ stat){
  const int t = threadIdx.x, b = blockIdx.x;
  __shared__ float Xl[128*20];
  __shared__ float W1l[32*36];
  __shared__ float W2l[32*36];
  __shared__ float Qp[128*36];
  __shared__ float sc1l[32], sh1l[32];
  __shared__ float ssum[32], ssq[32];
  __shared__ uint idxl[640];
  const float* fb = feat + (size_t)b*2048;
  for (int i4 = t; i4 < 512; i4 += 256){
    const float4 v = *(const float4*)&fb[i4*4];
    *(float4*)&Xl[(i4>>2)*20 + (i4&3)*4] = v;
  }
  { const float4 v = *(const float4*)&W1[t*4];
    *(float4*)&W1l[(t>>3)*36 + (t&7)*4] = v; }
  { const float4 v = *(const float4*)&W2[t*4];
    *(float4*)&W2l[(t>>3)*36 + (t&7)*4] = v; }
  const uint* ig = (const uint*)(idx + (size_t)b*2560);
  for (int i = t; i < 640; i += 256) idxl[i] = ig[i];
  if (t < 32){ ssum[t]=0.f; ssq[t]=0.f; bn_make(st1,32,g1,be1,sc1l,sh1l,t); }
  __syncthreads();
  const int p = t & 127, ch = t >> 7;
  const int c0 = __builtin_amdgcn_readfirstlane(ch*16);
  float pv[32];
  {
    float xi[16];
    #pragma unroll
    for (int c4 = 0; c4 < 4; ++c4){
      const float4 v = *(const float4*)&Xl[p*20 + c4*4];
      xi[c4*4]=v.x; xi[c4*4+1]=v.y; xi[c4*4+2]=v.z; xi[c4*4+3]=v.w;
    }
    float t1[32], qv[32];
    #pragma unroll
    for (int c = 0; c < 32; ++c){ t1[c]=0.f; qv[c]=0.f; }
    #pragma unroll
    for (int i = 0; i < 16; ++i){
      const float v = xi[i];
      #pragma unroll
      for (int c4 = 0; c4 < 8; ++c4){
        const float4 wa = *(const float4*)&W1l[i*36 + c4*4];
        const float4 wb = *(const float4*)&W1l[(16+i)*36 + c4*4];
        t1[c4*4+0]=fmaf(v,wa.x,t1[c4*4+0]); t1[c4*4+1]=fmaf(v,wa.y,t1[c4*4+1]);
        t1[c4*4+2]=fmaf(v,wa.z,t1[c4*4+2]); t1[c4*4+3]=fmaf(v,wa.w,t1[c4*4+3]);
        qv[c4*4+0]=fmaf(v,wb.x,qv[c4*4+0]); qv[c4*4+1]=fmaf(v,wb.y,qv[c4*4+1]);
        qv[c4*4+2]=fmaf(v,wb.z,qv[c4*4+2]); qv[c4*4+3]=fmaf(v,wb.w,qv[c4*4+3]);
      }
    }
    #pragma unroll
    for (int c = 0; c < 32; ++c){
      const float sc = sc1l[c];
      pv[c] = fmaf(t1[c] - qv[c] + B1[c], sc, sh1l[c]);
      qv[c] *= sc;
    }
    if (ch == 0){
      const int sw = p & 7;
      #pragma unroll
      for (int cg = 0; cg < 8; ++cg){
        const int scg = cg ^ sw;
        *(float4*)&Qp[p*36 + (scg<<2)] =
          make_float4(qv[cg*4], qv[cg*4+1], qv[cg*4+2], qv[cg*4+3]);
      }
    }
  }
  __syncthreads();
  float b2r[16];
  #pragma unroll
  for (int c = 0; c < 16; ++c) b2r[c] = B2[c0+c];
  float ls[16], lq[16];
  #pragma unroll
  for (int c = 0; c < 16; ++c){ ls[c]=0.f; lq[c]=0.f; }
  const uchar* mi = (const uchar*)idxl + p*20;
  #pragma unroll 1
  for (int e = 0; e < KK; ++e){
    const int j = mi[e];
    const int jb = j*36, jsw = j & 7;
    float h2[16];
    #pragma unroll
    for (int c = 0; c < 16; ++c) h2[c] = b2r[c];
    #pragma unroll
    for (int i4 = 0; i4 < 8; ++i4){
      const float4 q = *(const float4*)&Qp[jb + ((i4 ^ jsw)<<2)];
      float rr[4];
      rr[0]=fmaxf(pv[i4*4+0]+q.x,0.f); rr[1]=fmaxf(pv[i4*4+1]+q.y,0.f);
      rr[2]=fmaxf(pv[i4*4+2]+q.z,0.f); rr[3]=fmaxf(pv[i4*4+3]+q.w,0.f);
      #pragma unroll
      for (int u = 0; u < 4; ++u){
        const float r = rr[u];
        #pragma unroll
        for (int c4 = 0; c4 < 4; ++c4){
          const float4 w = *(const float4*)&W2l[(i4*4+u)*36 + c0 + c4*4];  // uniform broadcast
          h2[c4*4+0]=fmaf(r,w.x,h2[c4*4+0]); h2[c4*4+1]=fmaf(r,w.y,h2[c4*4+1]);
          h2[c4*4+2]=fmaf(r,w.z,h2[c4*4+2]); h2[c4*4+3]=fmaf(r,w.w,h2[c4*4+3]);
        }
      }
    }
    #pragma unroll
    for (int c = 0; c < 16; ++c){
      ls[c] += h2[c];
      lq[c] = fmaf(h2[c], h2[c], lq[c]);
    }
  }
  const int lane = t & 63;
  #pragma unroll
  for (int c = 0; c < 16; ++c){
    float a = ls[c], q = lq[c];
    #pragma unroll
    for (int m = 32; m; m >>= 1){ a += __shfl_xor(a,m,64); q += __shfl_xor(q,m,64); }
    if (lane == 0){ atomicAdd(&ssum[c0+c], a); atomicAdd(&ssq[c0+c], q); }
  }
  __syncthreads();
  if (t < 32){
    unsafeAtomicAdd(&stat[t], (double)ssum[t]);
    unsafeAtomicAdd(&stat[32+t], (double)ssq[t]);
  }
}

// ---------------- EC1 output: thread=(point, ch-half), 16 outputs, mean_k, then W3 ----------------
__global__ __launch_bounds__(256) void ec1_m(const float* __restrict__ feat,
    const uchar* __restrict__ idx, const float* __restrict__ W1, const float* __restrict__ B1,
    const double* __restrict__ st1, const float* __restrict__ g1, const float* __restrict__ be1,
    const float* __restrict__ W2, const float* __restrict__ B2,
    const double* __restrict__ st2, const float* __restrict__ g2, const float* __restrict__ be2,
    const float* __restrict__ W3, const float* __restrict__ B3,
    float* __restrict__ x1){
  const int t = threadIdx.x, b = blockIdx.x;
  __shared__ float Xl[128*20];
  __shared__ float W1l[32*36];
  __shared__ float W2l[32*36];   // bn2-scale folded
  __shared__ float W3l[32*36];
  __shared__ float Qp[128*36];
  __shared__ float mlds[128*33];
  __shared__ float sc1l[32], sh1l[32], sc2l[32], sh2l[32];
  __shared__ uint idxl[640];
  if (t < 32) bn_make(st1,32,g1,be1,sc1l,sh1l,t);
  else if (t < 64) bn_make(st2,32,g2,be2,sc2l,sh2l,t-32);
  __syncthreads();
  const float* fb = feat + (size_t)b*2048;
  for (int i4 = t; i4 < 512; i4 += 256){
    const float4 v = *(const float4*)&fb[i4*4];
    *(float4*)&Xl[(i4>>2)*20 + (i4&3)*4] = v;
  }
  { const float4 v = *(const float4*)&W1[t*4];
    *(float4*)&W1l[(t>>3)*36 + (t&7)*4] = v; }
  { const float4 v = *(const float4*)&W2[t*4];
    const int col = (t&7)*4;
    float4 w;
    w.x = v.x*sc2l[col]; w.y = v.y*sc2l[col+1]; w.z = v.z*sc2l[col+2]; w.w = v.w*sc2l[col+3];
    *(float4*)&W2l[(t>>3)*36 + col] = w; }
  { const float4 v = *(const float4*)&W3[t*4];
    *(float4*)&W3l[(t>>3)*36 + (t&7)*4] = v; }
  const uint* ig = (const uint*)(idx + (size_t)b*2560);
  for (int i = t; i < 640; i += 256) idxl[i] = ig[i];
  __syncthreads();
  const int p = t & 127, ch = t >> 7;
  const int c0 = __builtin_amdgcn_readfirstlane(ch*16);
  float pv[32];
  {
    float xi[16];
    #pragma unroll
    for (int c4 = 0; c4 < 4; ++c4){
      const float4 v = *(const float4*)&Xl[p*20 + c4*4];
      xi[c4*4]=v.x; xi[c4*4+1]=v.y; xi[c4*4+2]=v.z; xi[c4*4+3]=v.w;
    }
    float t1[32], qv[32];
    #pragma unroll
    for (int c = 0; c < 32; ++c){ t1[c]=0.f; qv[c]=0.f; }
    #pragma unroll
    for (int i = 0; i < 16; ++i){
      const float v = xi[i];
      #pragma unroll
      for (int c4 = 0; c4 < 8; ++c4){
        const float4 wa = *(const float4*)&W1l[i*36 + c4*4];
        const float4 wb = *(const float4*)&W1l[(16+i)*36 + c4*4];
        t1[c4*4+0]=fmaf(v,wa.x,t1[c4*4+0]); t1[c4*4+1]=fmaf(v,wa.y,t1[c4*4+1]);
        t1[c4*4+2]=fmaf(v,wa.z,t1[c4*4+2]); t1[c4*4+3]=fmaf(v,wa.w,t1[c4*4+3]);
        qv[c4*4+0]=fmaf(v,wb.x,qv[c4*4+0]); qv[c4*4+1]=fmaf(v,wb.y,qv[c4*4+1]);
        qv[c4*4+2]=fmaf(v,wb.z,qv[c4*4+2]); qv[c4*4+3]=fmaf(v,wb.w,qv[c4*4+3]);
      }
    }
    #pragma unroll
    for (int c = 0; c < 32; ++c){
      const float sc = sc1l[c];
      pv[c] = fmaf(t1[c] - qv[c] + B1[c], sc, sh1l[c]);
      qv[c] *= sc;
    }
    if (ch == 0){
      const int sw = p & 7;
      #pragma unroll
      for (int cg = 0; cg < 8; ++cg){
        const int scg = cg ^ sw;
        *(float4*)&Qp[p*36 + (scg<<2)] =
          make_float4(qv[cg*4], qv[cg*4+1], qv[cg*4+2], qv[cg*4+3]);
      }
    }
  }
  __syncthreads();
  float b2v[16];
  #pragma unroll
  for (int c = 0; c < 16; ++c) b2v[c] = fmaf(B2[c0+c], sc2l[c0+c], sh2l[c0+c]);
  float macc[16];
  #pragma unroll
  for (int c = 0; c < 16; ++c) macc[c] = 0.f;
  const uchar* mi = (const uchar*)idxl + p*20;
  #pragma unroll 1
  for (int e = 0; e < KK; ++e){
    const int j = mi[e];
    const int jb = j*36, jsw = j & 7;
    float h2[16];
    #pragma unroll
    for (int c = 0; c < 16; ++c) h2[c] = b2v[c];
    #pragma unroll
    for (int i4 = 0; i4 < 8; ++i4){
      const float4 q = *(const float4*)&Qp[jb + ((i4 ^ jsw)<<2)];
      float rr[4];
      rr[0]=fmaxf(pv[i4*4+0]+q.x,0.f); rr[1]=fmaxf(pv[i4*4+1]+q.y,0.f);
      rr[2]=fmaxf(pv[i4*4+2]+q.z,0.f); rr[3]=fmaxf(pv[i4*4+3]+q.w,0.f);
      #pragma unroll
      for (int u = 0; u < 4; ++u){
        const float r = rr[u];
        #pragma unroll
        for (int c4 = 0; c4 < 4; ++c4){
          const float4 w = *(const float4*)&W2l[(i4*4+u)*36 + c0 + c4*4];
          h2[c4*4+0]=fmaf(r,w.x,h2[c4*4+0]); h2[c4*4+1]=fmaf(r,w.y,h2[c4*4+1]);
          h2[c4*4+2]=fmaf(r,w.z,h2[c4*4+2]); h2[c4*4+3]=fmaf(r,w.w,h2[c4*4+3]);
        }
      }
    }
    #pragma unroll
    for (int c = 0; c < 16; ++c) macc[c] += fmaxf(h2[c], 0.f);
  }
  #pragma unroll
  for (int c = 0; c < 16; ++c) mlds[p*33 + c0 + c] = macc[c] * INVK;
  __syncthreads();
  // W3 phase: thread -> (point, 16-col group); W3 from LDS uniform broadcast
  const int pt = t & 127;
  const int og = c0;
  float o16[16];
  #pragma unroll
  for (int c = 0; c < 16; ++c) o16[c] = B3[og + c];
  #pragma unroll
  for (int i = 0; i < 32; ++i){
    const float v = mlds[pt*33 + i];
    #pragma unroll
    for (int c4 = 0; c4 < 4; ++c4){
      const float4 w = *(const float4*)&W3l[i*36 + og + c4*4];
      o16[c4*4+0]=fmaf(v,w.x,o16[c4*4+0]); o16[c4*4+1]=fmaf(v,w.y,o16[c4*4+1]);
      o16[c4*4+2]=fmaf(v,w.z,o16[c4*4+2]); o16[c4*4+3]=fmaf(v,w.w,o16[c4*4+3]);
    }
  }
  float* o = x1 + ((size_t)b*128 + pt)*32 + og;
  #pragma unroll
  for (int c4 = 0; c4 < 4; ++c4)
    *(float4*)&o[c4*4] = make_float4(o16[c4*4], o16[c4*4+1], o16[c4*4+2], o16[c4*4+3]);
}

// ---------------- EC2 h4 stats via separability ----------------
__global__ __launch_bounds__(256) void pqs4(const float* __restrict__ x1,
    const uchar* __restrict__ idx, const float* __restrict__ W4, const float* __restrict__ B4,
    double* __restrict__ stat){
  const int t = threadIdx.x, b = blockIdx.x;
  __shared__ float X1b[128*33];
  __shared__ float W4l[64*68];
  __shared__ float Qp4[128*68];
  __shared__ float ssum[64], ssq[64];
  __shared__ uint idxl[640];
  const float* xb = x1 + (size_t)b*4096;
  for (int i4 = t; i4 < 1024; i4 += 256){
    const float4 v = *(const float4*)&xb[i4*4];
    const int r = i4>>3, c = (i4&7)*4;
    X1b[r*33+c]=v.x; X1b[r*33+c+1]=v.y; X1b[r*33+c+2]=v.z; X1b[r*33+c+3]=v.w;
  }
  for (int i4 = t; i4 < 1024; i4 += 256){
    const float4 v = *(const float4*)&W4[i4*4];
    *(float4*)&W4l[(i4>>4)*68 + (i4&15)*4] = v;
  }
  const uint* ig = (const uint*)(idx + (size_t)b*2560);
  for (int i = t; i < 640; i += 256) idxl[i] = ig[i];
  if (t < 64){ ssum[t]=0.f; ssq[t]=0.f; }
  __syncthreads();
  const int p = t & 127;
  const int c0 = __builtin_amdgcn_readfirstlane((t>>7)*32);
  float t1[32], qv[32];
  #pragma unroll
  for (int c = 0; c < 32; ++c){ t1[c]=0.f; qv[c]=0.f; }
  #pragma unroll 4
  for (int i = 0; i < 32; ++i){
    const float v = X1b[p*33 + i];
    #pragma unroll
    for (int c4 = 0; c4 < 8; ++c4){
      const float4 wa = *(const float4*)&W4l[i*68 + c0 + c4*4];
      const float4 wb = *(const float4*)&W4l[(32+i)*68 + c0 + c4*4];
      t1[c4*4+0]=fmaf(v,wa.x,t1[c4*4+0]); t1[c4*4+1]=fmaf(v,wa.y,t1[c4*4+1]);
      t1[c4*4+2]=fmaf(v,wa.z,t1[c4*4+2]); t1[c4*4+3]=fmaf(v,wa.w,t1[c4*4+3]);
      qv[c4*4+0]=fmaf(v,wb.x,qv[c4*4+0]); qv[c4*4+1]=fmaf(v,wb.y,qv[c4*4+1]);
      qv[c4*4+2]=fmaf(v,wb.z,qv[c4*4+2]); qv[c4*4+3]=fmaf(v,wb.w,qv[c4*4+3]);
    }
  }
  float pv[32];
  #pragma unroll
  for (int c = 0; c < 32; ++c){
    pv[c] = t1[c] - qv[c] + B4[c0+c];
    Qp4[p*68 + c0 + c] = qv[c];
  }
  __syncthreads();
  const uchar* mi = (const uchar*)idxl + p*20;
  float Qs[32], Q2[32];
  #pragma unroll
  for (int c = 0; c < 32; ++c){ Qs[c]=0.f; Q2[c]=0.f; }
  #pragma unroll 1
  for (int k = 0; k < KK; ++k){
    const int j = (int)mi[k] * 68;
    #pragma unroll
    for (int c4 = 0; c4 < 8; ++c4){
      const float4 q = *(const float4*)&Qp4[j + c0 + c4*4];
      Qs[c4*4+0]+=q.x; Q2[c4*4+0]=fmaf(q.x,q.x,Q2[c4*4+0]);
      Qs[c4*4+1]+=q.y; Q2[c4*4+1]=fmaf(q.y,q.y,Q2[c4*4+1]);
      Qs[c4*4+2]+=q.z; Q2[c4*4+2]=fmaf(q.z,q.z,Q2[c4*4+2]);
      Qs[c4*4+3]+=q.w; Q2[c4*4+3]=fmaf(q.w,q.w,Q2[c4*4+3]);
    }
  }
  #pragma unroll
  for (int c = 0; c < 32; ++c){
    float a = fmaf(20.f, pv[c], Qs[c]);
    float q = fmaf(20.f*pv[c], pv[c], fmaf(2.f*pv[c], Qs[c], Q2[c]));
    #pragma unroll
    for (int m = 32; m; m >>= 1){ a += __shfl_xor(a,m,64); q += __shfl_xor(q,m,64); }
    if ((t & 63) == 0){ atomicAdd(&ssum[c0+c], a); atomicAdd(&ssq[c0+c], q); }
  }
  __syncthreads();
  if (t < 64){
    unsafeAtomicAdd(&stat[t], (double)ssum[t]);
    unsafeAtomicAdd(&stat[64+t], (double)ssq[t]);
  }
}

// ---------------- EC2 output: fully LDS-staged, QW buffer = W4l -> Qp4 -> W5l ----------------
__global__ __launch_bounds__(256) void ec2_m(const float* __restrict__ x1,
    const uchar* __restrict__ idx, const float* __restrict__ W4, const float* __restrict__ B4,
    const double* __restrict__ st4, const float* __restrict__ g4, const float* __restrict__ be4,
    const float* __restrict__ W5, const float* __restrict__ B5,
    float* __restrict__ x2){
  const int t = threadIdx.x, b = blockIdx.x;
  __shared__ float xm[128*68];   // X (stride 36) then mlds (stride 68)
  __shared__ float QW[128*68];   // W4l (stride 68) -> Qp4 -> W5l
  __shared__ float sc4l[64], sh4l[64];
  __shared__ uint idxl[640];
  if (t < 64) bn_make(st4, 64, g4, be4, sc4l, sh4l, t);
  const float* xb = x1 + (size_t)b*4096;
  for (int i4 = t; i4 < 1024; i4 += 256){
    const float4 v = *(const float4*)&xb[i4*4];
    *(float4*)&xm[(i4>>3)*36 + (i4&7)*4] = v;
  }
  for (int i4 = t; i4 < 1024; i4 += 256){
    const float4 v = *(const float4*)&W4[i4*4];
    *(float4*)&QW[(i4>>4)*68 + (i4&15)*4] = v;
  }
  const uint* ig = (const uint*)(idx + (size_t)b*2560);
  for (int i = t; i < 640; i += 256) idxl[i] = ig[i];
  __syncthreads();
  const int p = t & 127;
  const int c0 = __builtin_amdgcn_readfirstlane((t>>7)*32);
  float pv[32], qs[32];
  {
    float t1[32], qv[32];
    #pragma unroll
    for (int c = 0; c < 32; ++c){ t1[c]=0.f; qv[c]=0.f; }
    #pragma unroll 4
    for (int i = 0; i < 32; ++i){
      const float v = xm[p*36 + i];
      #pragma unroll
      for (int c4 = 0; c4 < 8; ++c4){
        const float4 wa = *(const float4*)&QW[i*68 + c0 + c4*4];
        const float4 wb = *(const float4*)&QW[(32+i)*68 + c0 + c4*4];
        t1[c4*4+0]=fmaf(v,wa.x,t1[c4*4+0]); t1[c4*4+1]=fmaf(v,wa.y,t1[c4*4+1]);
        t1[c4*4+2]=fmaf(v,wa.z,t1[c4*4+2]); t1[c4*4+3]=fmaf(v,wa.w,t1[c4*4+3]);
        qv[c4*4+0]=fmaf(v,wb.x,qv[c4*4+0]); qv[c4*4+1]=fmaf(v,wb.y,qv[c4*4+1]);
        qv[c4*4+2]=fmaf(v,wb.z,qv[c4*4+2]); qv[c4*4+3]=fmaf(v,wb.w,qv[c4*4+3]);
      }
    }
    #pragma unroll
    for (int c = 0; c < 32; ++c){
      const float sc = sc4l[c0+c];
      pv[c] = fmaf(t1[c] - qv[c] + B4[c0+c], sc, sh4l[c0+c]);
      qs[c] = qv[c]*sc;
    }
  }
  __syncthreads();   // all W4l reads done
  {
    const int sw = p & 7;
    #pragma unroll
    for (int cg = 0; cg < 8; ++cg){
      const int scg = cg ^ sw;
      *(float4*)&QW[p*68 + c0 + (scg<<2)] =
        make_float4(qs[cg*4], qs[cg*4+1], qs[cg*4+2], qs[cg*4+3]);
    }
  }
  __syncthreads();
  float macc[32];
  #pragma unroll
  for (int c = 0; c < 32; ++c) macc[c] = 0.f;
  const uchar* mi = (const uchar*)idxl + p*20;
  #pragma unroll 1
  for (int k = 0; k < KK; ++k){
    const int j = mi[k];
    const int jb = j*68 + c0, jsw = j & 7;
    #pragma unroll
    for (int c4 = 0; c4 < 8; ++c4){
      const float4 q = *(const float4*)&QW[jb + ((c4 ^ jsw)<<2)];
      macc[c4*4+0] += fmaxf(pv[c4*4+0] + q.x, 0.f);
      macc[c4*4+1] += fmaxf(pv[c4*4+1] + q.y, 0.f);
      macc[c4*4+2] += fmaxf(pv[c4*4+2] + q.z, 0.f);
      macc[c4*4+3] += fmaxf(pv[c4*4+3] + q.w, 0.f);
    }
  }
  #pragma unroll
  for (int c4 = 0; c4 < 8; ++c4)
    *(float4*)&xm[p*68 + c0 + c4*4] =
      make_float4(macc[c4*4]*INVK, macc[c4*4+1]*INVK, macc[c4*4+2]*INVK, macc[c4*4+3]*INVK);
  __syncthreads();   // all Qp4 reads done
  for (int i4 = t; i4 < 1024; i4 += 256){
    const float4 v = *(const float4*)&W5[i4*4];
    *(float4*)&QW[(i4>>4)*68 + (i4&15)*4] = v;
  }
  __syncthreads();
  // W5 phase: thread -> (point, 32-col group); W5 from LDS uniform broadcast
  float o[32];
  #pragma unroll
  for (int c = 0; c < 32; ++c) o[c] = B5[c0 + c];
  #pragma unroll 4
  for (int i = 0; i < 64; ++i){
    const float v = xm[p*68 + i];
    #pragma unroll
    for (int c4 = 0; c4 < 8; ++c4){
      const float4 w = *(const float4*)&QW[i*68 + c0 + c4*4];
      o[c4*4+0]=fmaf(v,w.x,o[c4*4+0]); o[c4*4+1]=fmaf(v,w.y,o[c4*4+1]);
      o[c4*4+2]=fmaf(v,w.z,o[c4*4+2]); o[c4*4+3]=fmaf(v,w.w,o[c4*4+3]);
    }
  }
  float* ox = x2 + ((size_t)b*128 + p)*64 + c0;
  #pragma unroll
  for (int c4 = 0; c4 < 8; ++c4)
    *(float4*)&ox[c4*4] = make_float4(o[c4*4], o[c4*4+1], o[c4*4+2], o[c4*4+3]);
}

// ---------------- global max over N + head MLP ----------------
__global__ __launch_bounds__(128) void head_kernel(const float* __restrict__ x2,
    const float* __restrict__ w1, const float* __restrict__ b1,
    const float* __restrict__ w2, const float* __restrict__ b2,
    const float* __restrict__ w3, const float* __restrict__ b3,
    float* __restrict__ out){
  const int b = blockIdx.x, t = threadIdx.x;
  __shared__ float gmax2[128];
  __shared__ float h1s[128];
  __shared__ float part[2];
  {
    const int c = t & 63, nh = t >> 6;
    const float* xb = x2 + (size_t)b * 128 * 64 + (size_t)nh * 64 * 64 + c;
    float m = -3.0e38f;
    for (int n = 0; n < 64; ++n) m = fmaxf(m, xb[n*64]);
    gmax2[t] = m;
  }
  __syncthreads();
  float a = b1[t];
  #pragma unroll
  for (int i = 0; i < 64; ++i) a = fmaf(fmaxf(gmax2[i], gmax2[64+i]), w1[i*128 + t], a);
  h1s[t] = fmaxf(a, 0.f);
  __syncthreads();
  float h2 = b2[t];
  #pragma unroll
  for (int i = 0; i < 128; ++i) h2 = fmaf(h1s[i], w2[i*128 + t], h2);
  h2 = fmaxf(h2, 0.f);
  float pr = h2 * w3[t];
  #pragma unroll
  for (int m = 32; m; m >>= 1) pr += __shfl_xor(pr, m, 64);
  if ((t & 63) == 0) part[t >> 6] = pr;
  __syncthreads();
  if (t == 0) out[b] = part[0] + part[1] + b3[0];
}

extern "C" void kernel_launch(void* const* d_in, const int* in_sizes, int n_in,
                              void* d_out, int out_size, void* d_ws, size_t ws_size,
                              hipStream_t stream) {
  const float* points = (const float*)d_in[0];
  const float* feat   = (const float*)d_in[1];
  const float* c1_w1  = (const float*)d_in[2];
  const float* c1_b1  = (const float*)d_in[3];
  const float* c1_g1  = (const float*)d_in[4];
  const float* c1_be1 = (const float*)d_in[5];
  const float* c1_w2  = (const float*)d_in[6];
  const float* c1_b2  = (const float*)d_in[7];
  const float* c1_g2  = (const float*)d_in[8];
  const float* c1_be2 = (const float*)d_in[9];
  const float* c1_w3  = (const float*)d_in[10];
  const float* c1_b3  = (const float*)d_in[11];
  const float* c2_w1  = (const float*)d_in[12];
  const float* c2_b1  = (const float*)d_in[13];
  const float* c2_g1  = (const float*)d_in[14];
  const float* c2_be1 = (const float*)d_in[15];
  const float* c2_w2  = (const float*)d_in[16];
  const float* c2_b2  = (const float*)d_in[17];
  const float* m_w1   = (const float*)d_in[18];
  const float* m_b1   = (const float*)d_in[19];
  const float* m_w2   = (const float*)d_in[20];
  const float* m_b2   = (const float*)d_in[21];
  const float* m_w3   = (const float*)d_in[22];
  const float* m_b3   = (const float*)d_in[23];
  float* out = (float*)d_out;

  char* ws = (char*)d_ws;
  const size_t NEDGE = (size_t)512 * 128 * KK;
  uchar*  idx1 = (uchar*)ws;
  uchar*  idx2 = (uchar*)(ws + NEDGE);
  float*  x1   = (float*)(ws + 2*NEDGE);                       // 8.39 MB
  float*  x2   = (float*)(ws + 2*NEDGE + (size_t)65536*32*4);  // 16.8 MB
  double* stats = (double*)(ws + 2*NEDGE + (size_t)65536*96*4);
  double* st1 = stats;         // [sum32 | sq32]  (h1)
  double* st2 = stats + 64;    // [sum32 | sq32]  (h2)
  double* st4 = stats + 128;   // [sum64 | sq64]  (h4)

  hipMemsetAsync(stats, 0, 256*sizeof(double), stream);

  knn1_kernel<<<512, 256, 0, stream>>>(points, idx1);
  pqs1      <<<512, 256, 0, stream>>>(feat, idx1, c1_w1, c1_b1, st1);
  ec1_s2    <<<512, 256, 0, stream>>>(feat, idx1, c1_w1, c1_b1, st1, c1_g1, c1_be1,
                                      c1_w2, c1_b2, st2);
  ec1_m     <<<512, 256, 0, stream>>>(feat, idx1, c1_w1, c1_b1, st1, c1_g1, c1_be1,
                                      c1_w2, c1_b2, st2, c1_g2, c1_be2, c1_w3, c1_b3, x1);
  knn2_kernel<<<512, 256, 0, stream>>>(x1, idx2);
  pqs4      <<<512, 256, 0, stream>>>(x1, idx2, c2_w1, c2_b1, st4);
  ec2_m     <<<512, 256, 0, stream>>>(x1, idx2, c2_w1, c2_b1, st4, c2_g1, c2_be1,
                                      c2_w2, c2_b2, x2);
  head_kernel<<<512, 128, 0, stream>>>(x2, m_w1, m_b1, m_w2, m_b2, m_w3, m_b3, out);
}

// Round 9
// 949.406 us; speedup vs baseline: 2.5010x; 1.7455x over previous
//
#include <hip/hip_runtime.h>
#include <math.h>

#define KK 20
#define INVN (1.0 / 1310720.0)   // 1 / (B*N*K)
#define INVK (1.0f / 20.0f)

typedef unsigned char uchar;
typedef unsigned int uint;

// BN scale/shift from accumulated double sums
__device__ inline void bn_make(const double* __restrict__ st, int C,
                               const float* __restrict__ g, const float* __restrict__ be,
                               float* scl, float* shl, int c){
  const double m = st[c]*INVN, v = st[C+c]*INVN - m*m;
  const float s = (float)((double)g[c] / sqrt(v + 1e-5));
  scl[c] = s; shl[c] = be[c] - (float)m*s;
}

// rank phase shared by both KNN kernels (stable top_k semantics)
__device__ inline void rank_rows(const float (*D)[132], int t, int b, int n0,
                                 uchar* __restrict__ idx_out){
  const int rhalf = t >> 7;
  const int j = t & 127;
  for (int rep = 0; rep < 32; ++rep){
    const int rr = rep*2 + rhalf;
    const float* Drow = D[rr];
    const float myd = Drow[j];
    int cnt = 0;
    #pragma unroll 8
    for (int q4 = 0; q4 < 32; ++q4){
      const float4 v = *(const float4*)&Drow[q4*4];
      const int j0 = q4*4;
      cnt += (v.x < myd) + ((v.x == myd) & (j0     < j));
      cnt += (v.y < myd) + ((v.y == myd) & (j0 + 1 < j));
      cnt += (v.z < myd) + ((v.z == myd) & (j0 + 2 < j));
      cnt += (v.w < myd) + ((v.w == myd) & (j0 + 3 < j));
    }
    if (cnt < KK) idx_out[((size_t)b*128 + n0 + rr)*KK + cnt] = (uchar)j;
  }
}

// ---------------- KNN on 2-D points ----------------
__global__ __launch_bounds__(256) void knn1_kernel(const float* __restrict__ pts,
                                                   uchar* __restrict__ idx_out){
  const int b = blockIdx.x, t = threadIdx.x;
  __shared__ float px[128], py[128], sq[128];
  __shared__ float D[64][132];
  const float* p = pts + (size_t)b * 256;
  { float v = p[t]; if (t & 1) py[t>>1] = v; else px[t>>1] = v; }
  __syncthreads();
  if (t < 128) sq[t] = px[t]*px[t] + py[t]*py[t];
  __syncthreads();
  const int r = t >> 2, cg = t & 3;
  for (int half = 0; half < 2; ++half){
    const int n = half*64 + r;
    const float xn = px[n], yn = py[n], sn = sq[n];
    for (int jj = 0; jj < 32; ++jj){
      const int j = cg + jj*4;
      float d = sn + sq[j] - 2.0f*(xn*px[j] + yn*py[j]);
      if (j == n) d = 3.0e38f;
      D[r][j] = d;
    }
    __syncthreads();
    rank_rows(D, t, b, half*64, idx_out);
    __syncthreads();
  }
}

// ---------------- KNN on 32-D features ----------------
__global__ __launch_bounds__(256) void knn2_kernel(const float* __restrict__ x1,
                                                   uchar* __restrict__ idx_out){
  const int b = blockIdx.x, t = threadIdx.x;
  __shared__ float xs[128][36];
  __shared__ float sq[128];
  __shared__ float D[64][132];
  const float* xb = x1 + (size_t)b * 4096;
  for (int i4 = t; i4 < 1024; i4 += 256){
    const float4 v = *(const float4*)&xb[i4*4];
    *(float4*)&xs[i4>>3][(i4&7)*4] = v;
  }
  __syncthreads();
  if (t < 128){
    float s = 0.f;
    #pragma unroll
    for (int c = 0; c < 32; ++c){ const float v = xs[t][c]; s = fmaf(v, v, s); }
    sq[t] = s;
  }
  __syncthreads();
  const int r = t >> 2, cg = t & 3;
  for (int half = 0; half < 2; ++half){
    const int n = half*64 + r;
    float xt[32];
    #pragma unroll
    for (int c4 = 0; c4 < 8; ++c4){
      const float4 v = *(const float4*)&xs[n][c4*4];
      xt[c4*4+0]=v.x; xt[c4*4+1]=v.y; xt[c4*4+2]=v.z; xt[c4*4+3]=v.w;
    }
    const float sn = sq[n];
    for (int jj = 0; jj < 32; ++jj){
      const int j = cg + jj*4;
      float dot = 0.f;
      #pragma unroll
      for (int c4 = 0; c4 < 8; ++c4){
        const float4 v = *(const float4*)&xs[j][c4*4];
        dot = fmaf(xt[c4*4+0], v.x, dot);
        dot = fmaf(xt[c4*4+1], v.y, dot);
        dot = fmaf(xt[c4*4+2], v.z, dot);
        dot = fmaf(xt[c4*4+3], v.w, dot);
      }
      float d = sn + sq[j] - 2.0f*dot;
      if (j == n) d = 3.0e38f;
      D[r][j] = d;
    }
    __syncthreads();
    rank_rows(D, t, b, half*64, idx_out);
    __syncthreads();
  }
}

// ---------------- EC1 layer-1 stats via separability: h1(i,j)=p_i+q_j ----------------
__global__ __launch_bounds__(256) void pqs1(const float* __restrict__ feat,
    const uchar* __restrict__ idx, const float* __restrict__ W1, const float* __restrict__ B1,
    double* __restrict__ stat){
  const int t = threadIdx.x, b = blockIdx.x;
  __shared__ float Xl[128*20];
  __shared__ float W1l[32*36];
  __shared__ float Qp[128*36];
  __shared__ float ssum[32], ssq[32];
  __shared__ uint idxl[640];
  const float* fb = feat + (size_t)b*2048;
  for (int i4 = t; i4 < 512; i4 += 256){
    const float4 v = *(const float4*)&fb[i4*4];
    *(float4*)&Xl[(i4>>2)*20 + (i4&3)*4] = v;
  }
  { const float4 v = *(const float4*)&W1[t*4];
    *(float4*)&W1l[(t>>3)*36 + (t&7)*4] = v; }
  const uint* ig = (const uint*)(idx + (size_t)b*2560);
  for (int i = t; i < 640; i += 256) idxl[i] = ig[i];
  if (t < 32){ ssum[t]=0.f; ssq[t]=0.f; }
  __syncthreads();
  const int p = t & 127;
  const int c0 = __builtin_amdgcn_readfirstlane((t>>7)*16);
  float xi[16];
  #pragma unroll
  for (int c4 = 0; c4 < 4; ++c4){
    const float4 v = *(const float4*)&Xl[p*20 + c4*4];
    xi[c4*4]=v.x; xi[c4*4+1]=v.y; xi[c4*4+2]=v.z; xi[c4*4+3]=v.w;
  }
  float t1[16], qv[16];
  #pragma unroll
  for (int c = 0; c < 16; ++c){ t1[c]=0.f; qv[c]=0.f; }
  #pragma unroll 4
  for (int i = 0; i < 16; ++i){
    const float v = xi[i];
    #pragma unroll
    for (int c4 = 0; c4 < 4; ++c4){
      const float4 wa = *(const float4*)&W1l[i*36 + c0 + c4*4];
      const float4 wb = *(const float4*)&W1l[(16+i)*36 + c0 + c4*4];
      t1[c4*4+0]=fmaf(v,wa.x,t1[c4*4+0]); t1[c4*4+1]=fmaf(v,wa.y,t1[c4*4+1]);
      t1[c4*4+2]=fmaf(v,wa.z,t1[c4*4+2]); t1[c4*4+3]=fmaf(v,wa.w,t1[c4*4+3]);
      qv[c4*4+0]=fmaf(v,wb.x,qv[c4*4+0]); qv[c4*4+1]=fmaf(v,wb.y,qv[c4*4+1]);
      qv[c4*4+2]=fmaf(v,wb.z,qv[c4*4+2]); qv[c4*4+3]=fmaf(v,wb.w,qv[c4*4+3]);
    }
  }
  float pv[16];
  #pragma unroll
  for (int c = 0; c < 16; ++c){
    pv[c] = t1[c] - qv[c] + B1[c0+c];
    Qp[p*36 + c0 + c] = qv[c];
  }
  __syncthreads();
  const uchar* mi = (const uchar*)idxl + p*20;
  float Qs[16], Q2[16];
  #pragma unroll
  for (int c = 0; c < 16; ++c){ Qs[c]=0.f; Q2[c]=0.f; }
  #pragma unroll 1
  for (int k = 0; k < KK; ++k){
    const int j = (int)mi[k] * 36;
    #pragma unroll
    for (int c4 = 0; c4 < 4; ++c4){
      const float4 q = *(const float4*)&Qp[j + c0 + c4*4];
      Qs[c4*4+0]+=q.x; Q2[c4*4+0]=fmaf(q.x,q.x,Q2[c4*4+0]);
      Qs[c4*4+1]+=q.y; Q2[c4*4+1]=fmaf(q.y,q.y,Q2[c4*4+1]);
      Qs[c4*4+2]+=q.z; Q2[c4*4+2]=fmaf(q.z,q.z,Q2[c4*4+2]);
      Qs[c4*4+3]+=q.w; Q2[c4*4+3]=fmaf(q.w,q.w,Q2[c4*4+3]);
    }
  }
  #pragma unroll
  for (int c = 0; c < 16; ++c){
    float a = fmaf(20.f, pv[c], Qs[c]);
    float q = fmaf(20.f*pv[c], pv[c], fmaf(2.f*pv[c], Qs[c], Q2[c]));
    #pragma unroll
    for (int m = 32; m; m >>= 1){ a += __shfl_xor(a,m,64); q += __shfl_xor(q,m,64); }
    if ((t & 63) == 0){ atomicAdd(&ssum[c0+c], a); atomicAdd(&ssq[c0+c], q); }
  }
  __syncthreads();
  if (t < 32){
    unsafeAtomicAdd(&stat[t], (double)ssum[t]);
    unsafeAtomicAdd(&stat[32+t], (double)ssq[t]);
  }
}

// ---- shared phase-1 for channel-per-lane EC1 kernels: build Pl/Ql (bn1 folded) ----
__device__ inline void ec1_build_pq(int t, const float* Xl, const float* W1l,
                                    const float* __restrict__ B1,
                                    const float* sc1l, const float* sh1l,
                                    float* Pl, float* Ql){
  const int p = t & 127;
  const int c0 = __builtin_amdgcn_readfirstlane((t>>7)*8);   // 4 octs x 8 ch
  float xi[16];
  #pragma unroll
  for (int c4 = 0; c4 < 4; ++c4){
    const float4 v = *(const float4*)&Xl[p*20 + c4*4];
    xi[c4*4]=v.x; xi[c4*4+1]=v.y; xi[c4*4+2]=v.z; xi[c4*4+3]=v.w;
  }
  float t1[8], qv[8];
  #pragma unroll
  for (int c = 0; c < 8; ++c){ t1[c]=0.f; qv[c]=0.f; }
  #pragma unroll 4
  for (int i = 0; i < 16; ++i){
    const float v = xi[i];
    const float4 wa0 = *(const float4*)&W1l[i*36 + c0];
    const float4 wa1 = *(const float4*)&W1l[i*36 + c0 + 4];
    const float4 wb0 = *(const float4*)&W1l[(16+i)*36 + c0];
    const float4 wb1 = *(const float4*)&W1l[(16+i)*36 + c0 + 4];
    t1[0]=fmaf(v,wa0.x,t1[0]); t1[1]=fmaf(v,wa0.y,t1[1]);
    t1[2]=fmaf(v,wa0.z,t1[2]); t1[3]=fmaf(v,wa0.w,t1[3]);
    t1[4]=fmaf(v,wa1.x,t1[4]); t1[5]=fmaf(v,wa1.y,t1[5]);
    t1[6]=fmaf(v,wa1.z,t1[6]); t1[7]=fmaf(v,wa1.w,t1[7]);
    qv[0]=fmaf(v,wb0.x,qv[0]); qv[1]=fmaf(v,wb0.y,qv[1]);
    qv[2]=fmaf(v,wb0.z,qv[2]); qv[3]=fmaf(v,wb0.w,qv[3]);
    qv[4]=fmaf(v,wb1.x,qv[4]); qv[5]=fmaf(v,wb1.y,qv[5]);
    qv[6]=fmaf(v,wb1.z,qv[6]); qv[7]=fmaf(v,wb1.w,qv[7]);
  }
  float pw[8], qw[8];
  #pragma unroll
  for (int c = 0; c < 8; ++c){
    const float sc = sc1l[c0+c];
    pw[c] = fmaf(t1[c] - qv[c] + B1[c0+c], sc, sh1l[c0+c]);
    qw[c] = qv[c]*sc;
  }
  *(float4*)&Pl[p*36 + c0]     = make_float4(pw[0],pw[1],pw[2],pw[3]);
  *(float4*)&Pl[p*36 + c0 + 4] = make_float4(pw[4],pw[5],pw[6],pw[7]);
  *(float4*)&Ql[p*36 + c0]     = make_float4(qw[0],qw[1],qw[2],qw[3]);
  *(float4*)&Ql[p*36 + c0 + 4] = make_float4(qw[4],qw[5],qw[6],qw[7]);
}

// ---------------- EC1 h2 stats: channel-per-lane, W2 column in registers ----------------
__global__ __launch_bounds__(512) void ec1_s2(const float* __restrict__ feat,
    const uchar* __restrict__ idx, const float* __restrict__ W1, const float* __restrict__ B1,
    const double* __restrict__ st1, const float* __restrict__ g1, const float* __restrict__ be1,
    const float* __restrict__ W2, const float* __restrict__ B2,
    double* __restrict__ stat){
  const int t = threadIdx.x, b = blockIdx.x;
  __shared__ float Xl[128*20];
  __shared__ float W1l[32*36];
  __shared__ float Pl[128*36];
  __shared__ float Ql[128*36];
  __shared__ float Rl[16*36];
  __shared__ float sc1l[32], sh1l[32];
  __shared__ float ssum[32], ssq[32];
  __shared__ uint idxl[640];
  const float* fb = feat + (size_t)b*2048;
  { const float4 v = *(const float4*)&fb[t*4];
    *(float4*)&Xl[(t>>2)*20 + (t&3)*4] = v; }
  if (t < 256){ const float4 v = *(const float4*)&W1[t*4];
    *(float4*)&W1l[(t>>3)*36 + (t&7)*4] = v; }
  const uint* ig = (const uint*)(idx + (size_t)b*2560);
  if (t < 512) idxl[t] = ig[t];
  for (int i = t + 512; i < 640; i += 512) idxl[i] = ig[i];
  if (t < 32){ ssum[t]=0.f; ssq[t]=0.f; bn_make(st1,32,g1,be1,sc1l,sh1l,t); }
  __syncthreads();
  ec1_build_pq(t, Xl, W1l, B1, sc1l, sh1l, Pl, Ql);
  __syncthreads();
  const int lane = t & 63, wv = t >> 6;
  const int c = lane & 31, lp = wv*2 + (lane>>5);
  float w2col[32];
  #pragma unroll 4
  for (int i = 0; i < 32; ++i) w2col[i] = W2[i*32 + c];
  const float b2c = B2[c];
  float ls = 0.f, lq = 0.f;
  #pragma unroll 1
  for (int pass = 0; pass < 8; ++pass){
    const int p = pass*16 + lp;
    const float pvc = Pl[p*36 + c];
    const uchar* mi = (const uchar*)idxl + p*20;
    #pragma unroll 1
    for (int e = 0; e < KK; ++e){
      const int j = mi[e];
      Rl[lp*36 + c] = fmaxf(pvc + Ql[j*36 + c], 0.f);
      float a0 = b2c, a1 = 0.f, a2 = 0.f, a3 = 0.f;
      #pragma unroll
      for (int i4 = 0; i4 < 8; ++i4){
        const float4 rv = *(const float4*)&Rl[lp*36 + i4*4];
        a0 = fmaf(rv.x, w2col[i4*4+0], a0);
        a1 = fmaf(rv.y, w2col[i4*4+1], a1);
        a2 = fmaf(rv.z, w2col[i4*4+2], a2);
        a3 = fmaf(rv.w, w2col[i4*4+3], a3);
      }
      const float hv = (a0 + a1) + (a2 + a3);
      ls += hv;
      lq = fmaf(hv, hv, lq);
    }
  }
  ls += __shfl_xor(ls, 32, 64);
  lq += __shfl_xor(lq, 32, 64);
  if (lane < 32){ atomicAdd(&ssum[c], ls); atomicAdd(&ssq[c], lq); }
  __syncthreads();
  if (t < 32){
    unsafeAtomicAdd(&stat[t], (double)ssum[t]);
    unsafeAtomicAdd(&stat[32+t], (double)ssq[t]);
  }
}

// ---------------- EC1 output: channel-per-lane, W2/W3 columns in registers ----------------
__global__ __launch_bounds__(512) void ec1_m(const float* __restrict__ feat,
    const uchar* __restrict__ idx, const float* __restrict__ W1, const float* __restrict__ B1,
    const double* __restrict__ st1, const float* __restrict__ g1, const float* __restrict__ be1,
    const float* __restrict__ W2, const float* __restrict__ B2,
    const double* __restrict__ st2, const float* __restrict__ g2, const float* __restrict__ be2,
    const float* __restrict__ W3, const float* __restrict__ B3,
    float* __restrict__ x1){
  const int t = threadIdx.x, b = blockIdx.x;
  __shared__ float Xl[128*20];
  __shared__ float W1l[32*36];
  __shared__ float Pl[128*36];
  __shared__ float Ql[128*36];
  __shared__ float Rl[16*36];
  __shared__ float sc1l[32], sh1l[32], sc2l[32], sh2l[32];
  __shared__ uint idxl[640];
  const float* fb = feat + (size_t)b*2048;
  { const float4 v = *(const float4*)&fb[t*4];
    *(float4*)&Xl[(t>>2)*20 + (t&3)*4] = v; }
  if (t < 256){ const float4 v = *(const float4*)&W1[t*4];
    *(float4*)&W1l[(t>>3)*36 + (t&7)*4] = v; }
  const uint* ig = (const uint*)(idx + (size_t)b*2560);
  if (t < 512) idxl[t] = ig[t];
  for (int i = t + 512; i < 640; i += 512) idxl[i] = ig[i];
  if (t < 32) bn_make(st1,32,g1,be1,sc1l,sh1l,t);
  else if (t < 64) bn_make(st2,32,g2,be2,sc2l,sh2l,t-32);
  __syncthreads();
  ec1_build_pq(t, Xl, W1l, B1, sc1l, sh1l, Pl, Ql);
  __syncthreads();
  const int lane = t & 63, wv = t >> 6;
  const int c = lane & 31, lp = wv*2 + (lane>>5);
  const float sc2c = sc2l[c];
  float w2col[32];
  #pragma unroll 4
  for (int i = 0; i < 32; ++i) w2col[i] = W2[i*32 + c] * sc2c;   // bn2 scale folded
  float w3col[32];
  #pragma unroll 4
  for (int i = 0; i < 32; ++i) w3col[i] = W3[i*32 + c];
  const float b2v = fmaf(B2[c], sc2c, sh2l[c]);
  const float b3c = B3[c];
  #pragma unroll 1
  for (int pass = 0; pass < 8; ++pass){
    const int p = pass*16 + lp;
    const float pvc = Pl[p*36 + c];
    const uchar* mi = (const uchar*)idxl + p*20;
    float macc = 0.f;
    #pragma unroll 1
    for (int e = 0; e < KK; ++e){
      const int j = mi[e];
      Rl[lp*36 + c] = fmaxf(pvc + Ql[j*36 + c], 0.f);
      float a0 = b2v, a1 = 0.f, a2 = 0.f, a3 = 0.f;
      #pragma unroll
      for (int i4 = 0; i4 < 8; ++i4){
        const float4 rv = *(const float4*)&Rl[lp*36 + i4*4];
        a0 = fmaf(rv.x, w2col[i4*4+0], a0);
        a1 = fmaf(rv.y, w2col[i4*4+1], a1);
        a2 = fmaf(rv.z, w2col[i4*4+2], a2);
        a3 = fmaf(rv.w, w2col[i4*4+3], a3);
      }
      macc += fmaxf((a0 + a1) + (a2 + a3), 0.f);
    }
    // W3 phase for this point via the same wave-private exchange row
    Rl[lp*36 + c] = macc * INVK;
    float o0 = b3c, o1 = 0.f, o2 = 0.f, o3 = 0.f;
    #pragma unroll
    for (int i4 = 0; i4 < 8; ++i4){
      const float4 mv = *(const float4*)&Rl[lp*36 + i4*4];
      o0 = fmaf(mv.x, w3col[i4*4+0], o0);
      o1 = fmaf(mv.y, w3col[i4*4+1], o1);
      o2 = fmaf(mv.z, w3col[i4*4+2], o2);
      o3 = fmaf(mv.w, w3col[i4*4+3], o3);
    }
    x1[((size_t)b*128 + p)*32 + c] = (o0 + o1) + (o2 + o3);
  }
}

// ---------------- EC2 h4 stats via separability ----------------
__global__ __launch_bounds__(256) void pqs4(const float* __restrict__ x1,
    const uchar* __restrict__ idx, const float* __restrict__ W4, const float* __restrict__ B4,
    double* __restrict__ stat){
  const int t = threadIdx.x, b = blockIdx.x;
  __shared__ float X1b[128*33];
  __shared__ float W4l[64*68];
  __shared__ float Qp4[128*68];
  __shared__ float ssum[64], ssq[64];
  __shared__ uint idxl[640];
  const float* xb = x1 + (size_t)b*4096;
  for (int i4 = t; i4 < 1024; i4 += 256){
    const float4 v = *(const float4*)&xb[i4*4];
    const int r = i4>>3, c = (i4&7)*4;
    X1b[r*33+c]=v.x; X1b[r*33+c+1]=v.y; X1b[r*33+c+2]=v.z; X1b[r*33+c+3]=v.w;
  }
  for (int i4 = t; i4 < 1024; i4 += 256){
    const float4 v = *(const float4*)&W4[i4*4];
    *(float4*)&W4l[(i4>>4)*68 + (i4&15)*4] = v;
  }
  const uint* ig = (const uint*)(idx + (size_t)b*2560);
  for (int i = t; i < 640; i += 256) idxl[i] = ig[i];
  if (t < 64){ ssum[t]=0.f; ssq[t]=0.f; }
  __syncthreads();
  const int p = t & 127;
  const int c0 = __builtin_amdgcn_readfirstlane((t>>7)*32);
  float t1[32], qv[32];
  #pragma unroll
  for (int c = 0; c < 32; ++c){ t1[c]=0.f; qv[c]=0.f; }
  #pragma unroll 4
  for (int i = 0; i < 32; ++i){
    const float v = X1b[p*33 + i];
    #pragma unroll
    for (int c4 = 0; c4 < 8; ++c4){
      const float4 wa = *(const float4*)&W4l[i*68 + c0 + c4*4];
      const float4 wb = *(const float4*)&W4l[(32+i)*68 + c0 + c4*4];
      t1[c4*4+0]=fmaf(v,wa.x,t1[c4*4+0]); t1[c4*4+1]=fmaf(v,wa.y,t1[c4*4+1]);
      t1[c4*4+2]=fmaf(v,wa.z,t1[c4*4+2]); t1[c4*4+3]=fmaf(v,wa.w,t1[c4*4+3]);
      qv[c4*4+0]=fmaf(v,wb.x,qv[c4*4+0]); qv[c4*4+1]=fmaf(v,wb.y,qv[c4*4+1]);
      qv[c4*4+2]=fmaf(v,wb.z,qv[c4*4+2]); qv[c4*4+3]=fmaf(v,wb.w,qv[c4*4+3]);
    }
  }
  float pv[32];
  #pragma unroll
  for (int c = 0; c < 32; ++c){
    pv[c] = t1[c] - qv[c] + B4[c0+c];
    Qp4[p*68 + c0 + c] = qv[c];
  }
  __syncthreads();
  const uchar* mi = (const uchar*)idxl + p*20;
  float Qs[32], Q2[32];
  #pragma unroll
  for (int c = 0; c < 32; ++c){ Qs[c]=0.f; Q2[c]=0.f; }
  #pragma unroll 1
  for (int k = 0; k < KK; ++k){
    const int j = (int)mi[k] * 68;
    #pragma unroll
    for (int c4 = 0; c4 < 8; ++c4){
      const float4 q = *(const float4*)&Qp4[j + c0 + c4*4];
      Qs[c4*4+0]+=q.x; Q2[c4*4+0]=fmaf(q.x,q.x,Q2[c4*4+0]);
      Qs[c4*4+1]+=q.y; Q2[c4*4+1]=fmaf(q.y,q.y,Q2[c4*4+1]);
      Qs[c4*4+2]+=q.z; Q2[c4*4+2]=fmaf(q.z,q.z,Q2[c4*4+2]);
      Qs[c4*4+3]+=q.w; Q2[c4*4+3]=fmaf(q.w,q.w,Q2[c4*4+3]);
    }
  }
  #pragma unroll
  for (int c = 0; c < 32; ++c){
    float a = fmaf(20.f, pv[c], Qs[c]);
    float q = fmaf(20.f*pv[c], pv[c], fmaf(2.f*pv[c], Qs[c], Q2[c]));
    #pragma unroll
    for (int m = 32; m; m >>= 1){ a += __shfl_xor(a,m,64); q += __shfl_xor(q,m,64); }
    if ((t & 63) == 0){ atomicAdd(&ssum[c0+c], a); atomicAdd(&ssq[c0+c], q); }
  }
  __syncthreads();
  if (t < 64){
    unsafeAtomicAdd(&stat[t], (double)ssum[t]);
    unsafeAtomicAdd(&stat[64+t], (double)ssq[t]);
  }
}

// ---------------- EC2 output: fully LDS-staged, QW buffer = W4l -> Qp4 -> W5l ----------------
__global__ __launch_bounds__(256) void ec2_m(const float* __restrict__ x1,
    const uchar* __restrict__ idx, const float* __restrict__ W4, const float* __restrict__ B4,
    const double* __restrict__ st4, const float* __restrict__ g4, const float* __restrict__ be4,
    const float* __restrict__ W5, const float* __restrict__ B5,
    float* __restrict__ x2){
  const int t = threadIdx.x, b = blockIdx.x;
  __shared__ float xm[128*68];   // X (stride 36) then mlds (stride 68)
  __shared__ float QW[128*68];   // W4l (stride 68) -> Qp4 -> W5l
  __shared__ float sc4l[64], sh4l[64];
  __shared__ uint idxl[640];
  if (t < 64) bn_make(st4, 64, g4, be4, sc4l, sh4l, t);
  const float* xb = x1 + (size_t)b*4096;
  for (int i4 = t; i4 < 1024; i4 += 256){
    const float4 v = *(const float4*)&xb[i4*4];
    *(float4*)&xm[(i4>>3)*36 + (i4&7)*4] = v;
  }
  for (int i4 = t; i4 < 1024; i4 += 256){
    const float4 v = *(const float4*)&W4[i4*4];
    *(float4*)&QW[(i4>>4)*68 + (i4&15)*4] = v;
  }
  const uint* ig = (const uint*)(idx + (size_t)b*2560);
  for (int i = t; i < 640; i += 256) idxl[i] = ig[i];
  __syncthreads();
  const int p = t & 127;
  const int c0 = __builtin_amdgcn_readfirstlane((t>>7)*32);
  float pv[32], qs[32];
  {
    float t1[32], qv[32];
    #pragma unroll
    for (int c = 0; c < 32; ++c){ t1[c]=0.f; qv[c]=0.f; }
    #pragma unroll 4
    for (int i = 0; i < 32; ++i){
      const float v = xm[p*36 + i];
      #pragma unroll
      for (int c4 = 0; c4 < 8; ++c4){
        const float4 wa = *(const float4*)&QW[i*68 + c0 + c4*4];
        const float4 wb = *(const float4*)&QW[(32+i)*68 + c0 + c4*4];
        t1[c4*4+0]=fmaf(v,wa.x,t1[c4*4+0]); t1[c4*4+1]=fmaf(v,wa.y,t1[c4*4+1]);
        t1[c4*4+2]=fmaf(v,wa.z,t1[c4*4+2]); t1[c4*4+3]=fmaf(v,wa.w,t1[c4*4+3]);
        qv[c4*4+0]=fmaf(v,wb.x,qv[c4*4+0]); qv[c4*4+1]=fmaf(v,wb.y,qv[c4*4+1]);
        qv[c4*4+2]=fmaf(v,wb.z,qv[c4*4+2]); qv[c4*4+3]=fmaf(v,wb.w,qv[c4*4+3]);
      }
    }
    #pragma unroll
    for (int c = 0; c < 32; ++c){
      const float sc = sc4l[c0+c];
      pv[c] = fmaf(t1[c] - qv[c] + B4[c0+c], sc, sh4l[c0+c]);
      qs[c] = qv[c]*sc;
    }
  }
  __syncthreads();   // all W4l reads done
  {
    const int sw = p & 7;
    #pragma unroll
    for (int cg = 0; cg < 8; ++cg){
      const int scg = cg ^ sw;
      *(float4*)&QW[p*68 + c0 + (scg<<2)] =
        make_float4(qs[cg*4], qs[cg*4+1], qs[cg*4+2], qs[cg*4+3]);
    }
  }
  __syncthreads();
  float macc[32];
  #pragma unroll
  for (int c = 0; c < 32; ++c) macc[c] = 0.f;
  const uchar* mi = (const uchar*)idxl + p*20;
  #pragma unroll 1
  for (int k = 0; k < KK; ++k){
    const int j = mi[k];
    const int jb = j*68 + c0, jsw = j & 7;
    #pragma unroll
    for (int c4 = 0; c4 < 8; ++c4){
      const float4 q = *(const float4*)&QW[jb + ((c4 ^ jsw)<<2)];
      macc[c4*4+0] += fmaxf(pv[c4*4+0] + q.x, 0.f);
      macc[c4*4+1] += fmaxf(pv[c4*4+1] + q.y, 0.f);
      macc[c4*4+2] += fmaxf(pv[c4*4+2] + q.z, 0.f);
      macc[c4*4+3] += fmaxf(pv[c4*4+3] + q.w, 0.f);
    }
  }
  #pragma unroll
  for (int c4 = 0; c4 < 8; ++c4)
    *(float4*)&xm[p*68 + c0 + c4*4] =
      make_float4(macc[c4*4]*INVK, macc[c4*4+1]*INVK, macc[c4*4+2]*INVK, macc[c4*4+3]*INVK);
  __syncthreads();   // all Qp4 reads done
  for (int i4 = t; i4 < 1024; i4 += 256){
    const float4 v = *(const float4*)&W5[i4*4];
    *(float4*)&QW[(i4>>4)*68 + (i4&15)*4] = v;
  }
  __syncthreads();
  float o[32];
  #pragma unroll
  for (int c = 0; c < 32; ++c) o[c] = B5[c0 + c];
  #pragma unroll 4
  for (int i = 0; i < 64; ++i){
    const float v = xm[p*68 + i];
    #pragma unroll
    for (int c4 = 0; c4 < 8; ++c4){
      const float4 w = *(const float4*)&QW[i*68 + c0 + c4*4];
      o[c4*4+0]=fmaf(v,w.x,o[c4*4+0]); o[c4*4+1]=fmaf(v,w.y,o[c4*4+1]);
      o[c4*4+2]=fmaf(v,w.z,o[c4*4+2]); o[c4*4+3]=fmaf(v,w.w,o[c4*4+3]);
    }
  }
  float* ox = x2 + ((size_t)b*128 + p)*64 + c0;
  #pragma unroll
  for (int c4 = 0; c4 < 8; ++c4)
    *(float4*)&ox[c4*4] = make_float4(o[c4*4], o[c4*4+1], o[c4*4+2], o[c4*4+3]);
}

// ---------------- global max over N + head MLP ----------------
__global__ __launch_bounds__(128) void head_kernel(const float* __restrict__ x2,
    const float* __restrict__ w1, const float* __restrict__ b1,
    const float* __restrict__ w2, const float* __restrict__ b2,
    const float* __restrict__ w3, const float* __restrict__ b3,
    float* __restrict__ out){
  const int b = blockIdx.x, t = threadIdx.x;
  __shared__ float gmax2[128];
  __shared__ float h1s[128];
  __shared__ float part[2];
  {
    const int c = t & 63, nh = t >> 6;
    const float* xb = x2 + (size_t)b * 128 * 64 + (size_t)nh * 64 * 64 + c;
    float m = -3.0e38f;
    for (int n = 0; n < 64; ++n) m = fmaxf(m, xb[n*64]);
    gmax2[t] = m;
  }
  __syncthreads();
  float a = b1[t];
  #pragma unroll
  for (int i = 0; i < 64; ++i) a = fmaf(fmaxf(gmax2[i], gmax2[64+i]), w1[i*128 + t], a);
  h1s[t] = fmaxf(a, 0.f);
  __syncthreads();
  float h2 = b2[t];
  #pragma unroll
  for (int i = 0; i < 128; ++i) h2 = fmaf(h1s[i], w2[i*128 + t], h2);
  h2 = fmaxf(h2, 0.f);
  float pr = h2 * w3[t];
  #pragma unroll
  for (int m = 32; m; m >>= 1) pr += __shfl_xor(pr, m, 64);
  if ((t & 63) == 0) part[t >> 6] = pr;
  __syncthreads();
  if (t == 0) out[b] = part[0] + part[1] + b3[0];
}

extern "C" void kernel_launch(void* const* d_in, const int* in_sizes, int n_in,
                              void* d_out, int out_size, void* d_ws, size_t ws_size,
                              hipStream_t stream) {
  const float* points = (const float*)d_in[0];
  const float* feat   = (const float*)d_in[1];
  const float* c1_w1  = (const float*)d_in[2];
  const float* c1_b1  = (const float*)d_in[3];
  const float* c1_g1  = (const float*)d_in[4];
  const float* c1_be1 = (const float*)d_in[5];
  const float* c1_w2  = (const float*)d_in[6];
  const float* c1_b2  = (const float*)d_in[7];
  const float* c1_g2  = (const float*)d_in[8];
  const float* c1_be2 = (const float*)d_in[9];
  const float* c1_w3  = (const float*)d_in[10];
  const float* c1_b3  = (const float*)d_in[11];
  const float* c2_w1  = (const float*)d_in[12];
  const float* c2_b1  = (const float*)d_in[13];
  const float* c2_g1  = (const float*)d_in[14];
  const float* c2_be1 = (const float*)d_in[15];
  const float* c2_w2  = (const float*)d_in[16];
  const float* c2_b2  = (const float*)d_in[17];
  const float* m_w1   = (const float*)d_in[18];
  const float* m_b1   = (const float*)d_in[19];
  const float* m_w2   = (const float*)d_in[20];
  const float* m_b2   = (const float*)d_in[21];
  const float* m_w3   = (const float*)d_in[22];
  const float* m_b3   = (const float*)d_in[23];
  float* out = (float*)d_out;

  char* ws = (char*)d_ws;
  const size_t NEDGE = (size_t)512 * 128 * KK;
  uchar*  idx1 = (uchar*)ws;
  uchar*  idx2 = (uchar*)(ws + NEDGE);
  float*  x1   = (float*)(ws + 2*NEDGE);                       // 8.39 MB
  float*  x2   = (float*)(ws + 2*NEDGE + (size_t)65536*32*4);  // 16.8 MB
  double* stats = (double*)(ws + 2*NEDGE + (size_t)65536*96*4);
  double* st1 = stats;         // [sum32 | sq32]  (h1)
  double* st2 = stats + 64;    // [sum32 | sq32]  (h2)
  double* st4 = stats + 128;   // [sum64 | sq64]  (h4)

  hipMemsetAsync(stats, 0, 256*sizeof(double), stream);

  knn1_kernel<<<512, 256, 0, stream>>>(points, idx1);
  pqs1      <<<512, 256, 0, stream>>>(feat, idx1, c1_w1, c1_b1, st1);
  ec1_s2    <<<512, 512, 0, stream>>>(feat, idx1, c1_w1, c1_b1, st1, c1_g1, c1_be1,
                                      c1_w2, c1_b2, st2);
  ec1_m     <<<512, 512, 0, stream>>>(feat, idx1, c1_w1, c1_b1, st1, c1_g1, c1_be1,
                                      c1_w2, c1_b2, st2, c1_g2, c1_be2, c1_w3, c1_b3, x1);
  knn2_kernel<<<512, 256, 0, stream>>>(x1, idx2);
  pqs4      <<<512, 256, 0, stream>>>(x1, idx2, c2_w1, c2_b1, st4);
  ec2_m     <<<512, 256, 0, stream>>>(x1, idx2, c2_w1, c2_b1, st4, c2_g1, c2_be1,
                                      c2_w2, c2_b2, x2);
  head_kernel<<<512, 128, 0, stream>>>(x2, m_w1, m_b1, m_w2, m_b2, m_w3, m_b3, out);
}

// Round 10
// 601.072 us; speedup vs baseline: 3.9504x; 1.5795x over previous
//
#include <hip/hip_runtime.h>
#include <math.h>

#define KK 20
#define INVN (1.0 / 1310720.0)   // 1 / (B*N*K)
#define INVK (1.0f / 20.0f)

typedef unsigned char uchar;
typedef unsigned int uint;
typedef unsigned long long ull;

// BN scale/shift from accumulated double sums
__device__ inline void bn_make(const double* __restrict__ st, int C,
                               const float* __restrict__ g, const float* __restrict__ be,
                               float* scl, float* shl, int c){
  const double m = st[c]*INVN, v = st[C+c]*INVN - m*m;
  const float s = (float)((double)g[c] / sqrt(v + 1e-5));
  scl[c] = s; shl[c] = be[c] - (float)m*s;
}

// float -> monotonic ordered uint (preserves total order on finite floats)
__device__ inline uint ord32(float f){
  uint u = __float_as_uint(f);
  return u ^ (((int)u >> 31) | 0x80000000u);
}

// rank 4 columns {jg, jg+32, jg+64, jg+96} of one D64 row, write top-20 slots.
// key = (ord32(d)<<32)|j is unique -> cnt = exact stable-top_k position.
__device__ inline void rank4(const ull* __restrict__ Drow, int jg,
                             uchar* __restrict__ obase){
  const ull k0 = Drow[jg], k1 = Drow[jg+32], k2 = Drow[jg+64], k3 = Drow[jg+96];
  int c0=0, c1=0, c2=0, c3=0;
  #pragma unroll 4
  for (int q = 0; q < 64; ++q){
    const ulonglong2 kk = *(const ulonglong2*)&Drow[q*2];
    c0 += (kk.x < k0) + (kk.y < k0);
    c1 += (kk.x < k1) + (kk.y < k1);
    c2 += (kk.x < k2) + (kk.y < k2);
    c3 += (kk.x < k3) + (kk.y < k3);
  }
  if (c0 < KK) obase[c0] = (uchar)jg;
  if (c1 < KK) obase[c1] = (uchar)(jg+32);
  if (c2 < KK) obase[c2] = (uchar)(jg+64);
  if (c3 < KK) obase[c3] = (uchar)(jg+96);
}

// ---------------- KNN on 2-D points (u64-key rank) ----------------
__global__ __launch_bounds__(256) void knn1_kernel(const float* __restrict__ pts,
                                                   uchar* __restrict__ idx_out){
  const int b = blockIdx.x, t = threadIdx.x;
  __shared__ float px[128], py[128], sq[128];
  __shared__ ull D64[32*130];
  const float* p = pts + (size_t)b * 256;
  { float v = p[t]; if (t & 1) py[t>>1] = v; else px[t>>1] = v; }
  __syncthreads();
  if (t < 128) sq[t] = px[t]*px[t] + py[t]*py[t];
  __syncthreads();
  const int lr = t & 31, cgD = t >> 5;   // distance phase: row lr, col-group cgD (16 cols)
  const int jg = t & 31, rg = t >> 5;    // rank phase: col jg, row-group rg
  for (int pass = 0; pass < 4; ++pass){
    const int r0 = pass*32;
    const int rr = r0 + lr;
    const float xn = px[rr], yn = py[rr], sn = sq[rr];
    #pragma unroll
    for (int uu = 0; uu < 8; ++uu){
      ulonglong2 kk;
      #pragma unroll
      for (int v = 0; v < 2; ++v){
        const int j = cgD*16 + uu*2 + v;
        float d = sn + sq[j] - 2.0f*(xn*px[j] + yn*py[j]);
        if (j == rr) d = 3.0e38f;
        const ull key = ((ull)ord32(d) << 32) | (uint)j;
        if (v == 0) kk.x = key; else kk.y = key;
      }
      *(ulonglong2*)&D64[lr*130 + cgD*16 + uu*2] = kk;
    }
    __syncthreads();
    #pragma unroll 1
    for (int rs = 0; rs < 4; ++rs){
      const int lrr = rg + rs*8;
      rank4(&D64[lrr*130], jg, idx_out + ((size_t)b*128 + r0 + lrr)*KK);
    }
    __syncthreads();
  }
}

// ---------------- KNN on 32-D features (u64-key rank) ----------------
__global__ __launch_bounds__(256) void knn2_kernel(const float* __restrict__ x1,
                                                   uchar* __restrict__ idx_out){
  const int b = blockIdx.x, t = threadIdx.x;
  __shared__ float xs[128][36];
  __shared__ float sq[128];
  __shared__ ull D64[32*130];
  const float* xb = x1 + (size_t)b * 4096;
  for (int i4 = t; i4 < 1024; i4 += 256){
    const float4 v = *(const float4*)&xb[i4*4];
    *(float4*)&xs[i4>>3][(i4&7)*4] = v;
  }
  __syncthreads();
  if (t < 128){
    float s = 0.f;
    #pragma unroll
    for (int c = 0; c < 32; ++c){ const float v = xs[t][c]; s = fmaf(v, v, s); }
    sq[t] = s;
  }
  __syncthreads();
  const int lr = t & 31, cgD = t >> 5;
  const int jg = t & 31, rg = t >> 5;
  for (int pass = 0; pass < 4; ++pass){
    const int r0 = pass*32;
    const int rr = r0 + lr;
    float xt[32];
    #pragma unroll
    for (int c4 = 0; c4 < 8; ++c4){
      const float4 v = *(const float4*)&xs[rr][c4*4];
      xt[c4*4+0]=v.x; xt[c4*4+1]=v.y; xt[c4*4+2]=v.z; xt[c4*4+3]=v.w;
    }
    const float sn = sq[rr];
    #pragma unroll 2
    for (int uu = 0; uu < 8; ++uu){
      ulonglong2 kk;
      #pragma unroll
      for (int v = 0; v < 2; ++v){
        const int j = cgD*16 + uu*2 + v;
        float dot = 0.f;
        #pragma unroll
        for (int c4 = 0; c4 < 8; ++c4){
          const float4 xv = *(const float4*)&xs[j][c4*4];   // uniform broadcast per half-wave
          dot = fmaf(xt[c4*4+0], xv.x, dot);
          dot = fmaf(xt[c4*4+1], xv.y, dot);
          dot = fmaf(xt[c4*4+2], xv.z, dot);
          dot = fmaf(xt[c4*4+3], xv.w, dot);
        }
        float d = sn + sq[j] - 2.0f*dot;
        if (j == rr) d = 3.0e38f;
        const ull key = ((ull)ord32(d) << 32) | (uint)j;
        if (v == 0) kk.x = key; else kk.y = key;
      }
      *(ulonglong2*)&D64[lr*130 + cgD*16 + uu*2] = kk;
    }
    __syncthreads();
    #pragma unroll 1
    for (int rs = 0; rs < 4; ++rs){
      const int lrr = rg + rs*8;
      rank4(&D64[lrr*130], jg, idx_out + ((size_t)b*128 + r0 + lrr)*KK);
    }
    __syncthreads();
  }
}

// ---------------- EC1 layer-1 stats via separability: h1(i,j)=p_i+q_j ----------------
__global__ __launch_bounds__(256) void pqs1(const float* __restrict__ feat,
    const uchar* __restrict__ idx, const float* __restrict__ W1, const float* __restrict__ B1,
    double* __restrict__ stat){
  const int t = threadIdx.x, b = blockIdx.x;
  __shared__ float Xl[128*20];
  __shared__ float W1l[32*36];
  __shared__ float Qp[128*36];
  __shared__ float ssum[32], ssq[32];
  __shared__ uint idxl[640];
  const float* fb = feat + (size_t)b*2048;
  for (int i4 = t; i4 < 512; i4 += 256){
    const float4 v = *(const float4*)&fb[i4*4];
    *(float4*)&Xl[(i4>>2)*20 + (i4&3)*4] = v;
  }
  { const float4 v = *(const float4*)&W1[t*4];
    *(float4*)&W1l[(t>>3)*36 + (t&7)*4] = v; }
  const uint* ig = (const uint*)(idx + (size_t)b*2560);
  for (int i = t; i < 640; i += 256) idxl[i] = ig[i];
  if (t < 32){ ssum[t]=0.f; ssq[t]=0.f; }
  __syncthreads();
  const int p = t & 127;
  const int c0 = __builtin_amdgcn_readfirstlane((t>>7)*16);
  float xi[16];
  #pragma unroll
  for (int c4 = 0; c4 < 4; ++c4){
    const float4 v = *(const float4*)&Xl[p*20 + c4*4];
    xi[c4*4]=v.x; xi[c4*4+1]=v.y; xi[c4*4+2]=v.z; xi[c4*4+3]=v.w;
  }
  float t1[16], qv[16];
  #pragma unroll
  for (int c = 0; c < 16; ++c){ t1[c]=0.f; qv[c]=0.f; }
  #pragma unroll 4
  for (int i = 0; i < 16; ++i){
    const float v = xi[i];
    #pragma unroll
    for (int c4 = 0; c4 < 4; ++c4){
      const float4 wa = *(const float4*)&W1l[i*36 + c0 + c4*4];
      const float4 wb = *(const float4*)&W1l[(16+i)*36 + c0 + c4*4];
      t1[c4*4+0]=fmaf(v,wa.x,t1[c4*4+0]); t1[c4*4+1]=fmaf(v,wa.y,t1[c4*4+1]);
      t1[c4*4+2]=fmaf(v,wa.z,t1[c4*4+2]); t1[c4*4+3]=fmaf(v,wa.w,t1[c4*4+3]);
      qv[c4*4+0]=fmaf(v,wb.x,qv[c4*4+0]); qv[c4*4+1]=fmaf(v,wb.y,qv[c4*4+1]);
      qv[c4*4+2]=fmaf(v,wb.z,qv[c4*4+2]); qv[c4*4+3]=fmaf(v,wb.w,qv[c4*4+3]);
    }
  }
  float pv[16];
  #pragma unroll
  for (int c = 0; c < 16; ++c){
    pv[c] = t1[c] - qv[c] + B1[c0+c];
    Qp[p*36 + c0 + c] = qv[c];
  }
  __syncthreads();
  const uchar* mi = (const uchar*)idxl + p*20;
  float Qs[16], Q2[16];
  #pragma unroll
  for (int c = 0; c < 16; ++c){ Qs[c]=0.f; Q2[c]=0.f; }
  #pragma unroll 1
  for (int k = 0; k < KK; ++k){
    const int j = (int)mi[k] * 36;
    #pragma unroll
    for (int c4 = 0; c4 < 4; ++c4){
      const float4 q = *(const float4*)&Qp[j + c0 + c4*4];
      Qs[c4*4+0]+=q.x; Q2[c4*4+0]=fmaf(q.x,q.x,Q2[c4*4+0]);
      Qs[c4*4+1]+=q.y; Q2[c4*4+1]=fmaf(q.y,q.y,Q2[c4*4+1]);
      Qs[c4*4+2]+=q.z; Q2[c4*4+2]=fmaf(q.z,q.z,Q2[c4*4+2]);
      Qs[c4*4+3]+=q.w; Q2[c4*4+3]=fmaf(q.w,q.w,Q2[c4*4+3]);
    }
  }
  #pragma unroll
  for (int c = 0; c < 16; ++c){
    float a = fmaf(20.f, pv[c], Qs[c]);
    float q = fmaf(20.f*pv[c], pv[c], fmaf(2.f*pv[c], Qs[c], Q2[c]));
    #pragma unroll
    for (int m = 32; m; m >>= 1){ a += __shfl_xor(a,m,64); q += __shfl_xor(q,m,64); }
    if ((t & 63) == 0){ atomicAdd(&ssum[c0+c], a); atomicAdd(&ssq[c0+c], q); }
  }
  __syncthreads();
  if (t < 32){
    unsafeAtomicAdd(&stat[t], (double)ssum[t]);
    unsafeAtomicAdd(&stat[32+t], (double)ssq[t]);
  }
}

// ---- shared phase-1 for channel-per-lane EC1 kernels: build Pl/Ql (bn1 folded) ----
__device__ inline void ec1_build_pq(int t, const float* Xl, const float* W1l,
                                    const float* __restrict__ B1,
                                    const float* sc1l, const float* sh1l,
                                    float* Pl, float* Ql){
  const int p = t & 127;
  const int c0 = __builtin_amdgcn_readfirstlane((t>>7)*8);   // 4 octs x 8 ch
  float xi[16];
  #pragma unroll
  for (int c4 = 0; c4 < 4; ++c4){
    const float4 v = *(const float4*)&Xl[p*20 + c4*4];
    xi[c4*4]=v.x; xi[c4*4+1]=v.y; xi[c4*4+2]=v.z; xi[c4*4+3]=v.w;
  }
  float t1[8], qv[8];
  #pragma unroll
  for (int c = 0; c < 8; ++c){ t1[c]=0.f; qv[c]=0.f; }
  #pragma unroll 4
  for (int i = 0; i < 16; ++i){
    const float v = xi[i];
    const float4 wa0 = *(const float4*)&W1l[i*36 + c0];
    const float4 wa1 = *(const float4*)&W1l[i*36 + c0 + 4];
    const float4 wb0 = *(const float4*)&W1l[(16+i)*36 + c0];
    const float4 wb1 = *(const float4*)&W1l[(16+i)*36 + c0 + 4];
    t1[0]=fmaf(v,wa0.x,t1[0]); t1[1]=fmaf(v,wa0.y,t1[1]);
    t1[2]=fmaf(v,wa0.z,t1[2]); t1[3]=fmaf(v,wa0.w,t1[3]);
    t1[4]=fmaf(v,wa1.x,t1[4]); t1[5]=fmaf(v,wa1.y,t1[5]);
    t1[6]=fmaf(v,wa1.z,t1[6]); t1[7]=fmaf(v,wa1.w,t1[7]);
    qv[0]=fmaf(v,wb0.x,qv[0]); qv[1]=fmaf(v,wb0.y,qv[1]);
    qv[2]=fmaf(v,wb0.z,qv[2]); qv[3]=fmaf(v,wb0.w,qv[3]);
    qv[4]=fmaf(v,wb1.x,qv[4]); qv[5]=fmaf(v,wb1.y,qv[5]);
    qv[6]=fmaf(v,wb1.z,qv[6]); qv[7]=fmaf(v,wb1.w,qv[7]);
  }
  float pw[8], qw[8];
  #pragma unroll
  for (int c = 0; c < 8; ++c){
    const float sc = sc1l[c0+c];
    pw[c] = fmaf(t1[c] - qv[c] + B1[c0+c], sc, sh1l[c0+c]);
    qw[c] = qv[c]*sc;
  }
  *(float4*)&Pl[p*36 + c0]     = make_float4(pw[0],pw[1],pw[2],pw[3]);
  *(float4*)&Pl[p*36 + c0 + 4] = make_float4(pw[4],pw[5],pw[6],pw[7]);
  *(float4*)&Ql[p*36 + c0]     = make_float4(qw[0],qw[1],qw[2],qw[3]);
  *(float4*)&Ql[p*36 + c0 + 4] = make_float4(qw[4],qw[5],qw[6],qw[7]);
}

// ---------------- EC1 h2 stats: channel-per-lane, W2 column in registers ----------------
__global__ __launch_bounds__(512) void ec1_s2(const float* __restrict__ feat,
    const uchar* __restrict__ idx, const float* __restrict__ W1, const float* __restrict__ B1,
    const double* __restrict__ st1, const float* __restrict__ g1, const float* __restrict__ be1,
    const float* __restrict__ W2, const float* __restrict__ B2,
    double* __restrict__ stat){
  const int t = threadIdx.x, b = blockIdx.x;
  __shared__ float Xl[128*20];
  __shared__ float W1l[32*36];
  __shared__ float Pl[128*36];
  __shared__ float Ql[128*36];
  __shared__ float Rl[16*36];
  __shared__ float sc1l[32], sh1l[32];
  __shared__ float ssum[32], ssq[32];
  __shared__ uint idxl[640];
  const float* fb = feat + (size_t)b*2048;
  { const float4 v = *(const float4*)&fb[t*4];
    *(float4*)&Xl[(t>>2)*20 + (t&3)*4] = v; }
  if (t < 256){ const float4 v = *(const float4*)&W1[t*4];
    *(float4*)&W1l[(t>>3)*36 + (t&7)*4] = v; }
  const uint* ig = (const uint*)(idx + (size_t)b*2560);
  if (t < 512) idxl[t] = ig[t];
  for (int i = t + 512; i < 640; i += 512) idxl[i] = ig[i];
  if (t < 32){ ssum[t]=0.f; ssq[t]=0.f; bn_make(st1,32,g1,be1,sc1l,sh1l,t); }
  __syncthreads();
  ec1_build_pq(t, Xl, W1l, B1, sc1l, sh1l, Pl, Ql);
  __syncthreads();
  const int lane = t & 63, wv = t >> 6;
  const int c = lane & 31, lp = wv*2 + (lane>>5);
  float w2col[32];
  #pragma unroll 4
  for (int i = 0; i < 32; ++i) w2col[i] = W2[i*32 + c];
  const float b2c = B2[c];
  float ls = 0.f, lq = 0.f;
  #pragma unroll 1
  for (int pass = 0; pass < 8; ++pass){
    const int p = pass*16 + lp;
    const float pvc = Pl[p*36 + c];
    const uchar* mi = (const uchar*)idxl + p*20;
    #pragma unroll 1
    for (int e = 0; e < KK; ++e){
      const int j = mi[e];
      Rl[lp*36 + c] = fmaxf(pvc + Ql[j*36 + c], 0.f);
      float a0 = b2c, a1 = 0.f, a2 = 0.f, a3 = 0.f;
      #pragma unroll
      for (int i4 = 0; i4 < 8; ++i4){
        const float4 rv = *(const float4*)&Rl[lp*36 + i4*4];
        a0 = fmaf(rv.x, w2col[i4*4+0], a0);
        a1 = fmaf(rv.y, w2col[i4*4+1], a1);
        a2 = fmaf(rv.z, w2col[i4*4+2], a2);
        a3 = fmaf(rv.w, w2col[i4*4+3], a3);
      }
      const float hv = (a0 + a1) + (a2 + a3);
      ls += hv;
      lq = fmaf(hv, hv, lq);
    }
  }
  ls += __shfl_xor(ls, 32, 64);
  lq += __shfl_xor(lq, 32, 64);
  if (lane < 32){ atomicAdd(&ssum[c], ls); atomicAdd(&ssq[c], lq); }
  __syncthreads();
  if (t < 32){
    unsafeAtomicAdd(&stat[t], (double)ssum[t]);
    unsafeAtomicAdd(&stat[32+t], (double)ssq[t]);
  }
}

// ---------------- EC1 output: channel-per-lane, W2/W3 columns in registers ----------------
__global__ __launch_bounds__(512) void ec1_m(const float* __restrict__ feat,
    const uchar* __restrict__ idx, const float* __restrict__ W1, const float* __restrict__ B1,
    const double* __restrict__ st1, const float* __restrict__ g1, const float* __restrict__ be1,
    const float* __restrict__ W2, const float* __restrict__ B2,
    const double* __restrict__ st2, const float* __restrict__ g2, const float* __restrict__ be2,
    const float* __restrict__ W3, const float* __restrict__ B3,
    float* __restrict__ x1){
  const int t = threadIdx.x, b = blockIdx.x;
  __shared__ float Xl[128*20];
  __shared__ float W1l[32*36];
  __shared__ float Pl[128*36];
  __shared__ float Ql[128*36];
  __shared__ float Rl[16*36];
  __shared__ float sc1l[32], sh1l[32], sc2l[32], sh2l[32];
  __shared__ uint idxl[640];
  const float* fb = feat + (size_t)b*2048;
  { const float4 v = *(const float4*)&fb[t*4];
    *(float4*)&Xl[(t>>2)*20 + (t&3)*4] = v; }
  if (t < 256){ const float4 v = *(const float4*)&W1[t*4];
    *(float4*)&W1l[(t>>3)*36 + (t&7)*4] = v; }
  const uint* ig = (const uint*)(idx + (size_t)b*2560);
  if (t < 512) idxl[t] = ig[t];
  for (int i = t + 512; i < 640; i += 512) idxl[i] = ig[i];
  if (t < 32) bn_make(st1,32,g1,be1,sc1l,sh1l,t);
  else if (t < 64) bn_make(st2,32,g2,be2,sc2l,sh2l,t-32);
  __syncthreads();
  ec1_build_pq(t, Xl, W1l, B1, sc1l, sh1l, Pl, Ql);
  __syncthreads();
  const int lane = t & 63, wv = t >> 6;
  const int c = lane & 31, lp = wv*2 + (lane>>5);
  const float sc2c = sc2l[c];
  float w2col[32];
  #pragma unroll 4
  for (int i = 0; i < 32; ++i) w2col[i] = W2[i*32 + c] * sc2c;   // bn2 scale folded
  float w3col[32];
  #pragma unroll 4
  for (int i = 0; i < 32; ++i) w3col[i] = W3[i*32 + c];
  const float b2v = fmaf(B2[c], sc2c, sh2l[c]);
  const float b3c = B3[c];
  #pragma unroll 1
  for (int pass = 0; pass < 8; ++pass){
    const int p = pass*16 + lp;
    const float pvc = Pl[p*36 + c];
    const uchar* mi = (const uchar*)idxl + p*20;
    float macc = 0.f;
    #pragma unroll 1
    for (int e = 0; e < KK; ++e){
      const int j = mi[e];
      Rl[lp*36 + c] = fmaxf(pvc + Ql[j*36 + c], 0.f);
      float a0 = b2v, a1 = 0.f, a2 = 0.f, a3 = 0.f;
      #pragma unroll
      for (int i4 = 0; i4 < 8; ++i4){
        const float4 rv = *(const float4*)&Rl[lp*36 + i4*4];
        a0 = fmaf(rv.x, w2col[i4*4+0], a0);
        a1 = fmaf(rv.y, w2col[i4*4+1], a1);
        a2 = fmaf(rv.z, w2col[i4*4+2], a2);
        a3 = fmaf(rv.w, w2col[i4*4+3], a3);
      }
      macc += fmaxf((a0 + a1) + (a2 + a3), 0.f);
    }
    // W3 phase for this point via the same wave-private exchange row
    Rl[lp*36 + c] = macc * INVK;
    float o0 = b3c, o1 = 0.f, o2 = 0.f, o3 = 0.f;
    #pragma unroll
    for (int i4 = 0; i4 < 8; ++i4){
      const float4 mv = *(const float4*)&Rl[lp*36 + i4*4];
      o0 = fmaf(mv.x, w3col[i4*4+0], o0);
      o1 = fmaf(mv.y, w3col[i4*4+1], o1);
      o2 = fmaf(mv.z, w3col[i4*4+2], o2);
      o3 = fmaf(mv.w, w3col[i4*4+3], o3);
    }
    x1[((size_t)b*128 + p)*32 + c] = (o0 + o1) + (o2 + o3);
  }
}

// ---------------- EC2 h4 stats via separability ----------------
__global__ __launch_bounds__(256) void pqs4(const float* __restrict__ x1,
    const uchar* __restrict__ idx, const float* __restrict__ W4, const float* __restrict__ B4,
    double* __restrict__ stat){
  const int t = threadIdx.x, b = blockIdx.x;
  __shared__ float X1b[128*33];
  __shared__ float W4l[64*68];
  __shared__ float Qp4[128*68];
  __shared__ float ssum[64], ssq[64];
  __shared__ uint idxl[640];
  const float* xb = x1 + (size_t)b*4096;
  for (int i4 = t; i4 < 1024; i4 += 256){
    const float4 v = *(const float4*)&xb[i4*4];
    const int r = i4>>3, c = (i4&7)*4;
    X1b[r*33+c]=v.x; X1b[r*33+c+1]=v.y; X1b[r*33+c+2]=v.z; X1b[r*33+c+3]=v.w;
  }
  for (int i4 = t; i4 < 1024; i4 += 256){
    const float4 v = *(const float4*)&W4[i4*4];
    *(float4*)&W4l[(i4>>4)*68 + (i4&15)*4] = v;
  }
  const uint* ig = (const uint*)(idx + (size_t)b*2560);
  for (int i = t; i < 640; i += 256) idxl[i] = ig[i];
  if (t < 64){ ssum[t]=0.f; ssq[t]=0.f; }
  __syncthreads();
  const int p = t & 127;
  const int c0 = __builtin_amdgcn_readfirstlane((t>>7)*32);
  float t1[32], qv[32];
  #pragma unroll
  for (int c = 0; c < 32; ++c){ t1[c]=0.f; qv[c]=0.f; }
  #pragma unroll 4
  for (int i = 0; i < 32; ++i){
    const float v = X1b[p*33 + i];
    #pragma unroll
    for (int c4 = 0; c4 < 8; ++c4){
      const float4 wa = *(const float4*)&W4l[i*68 + c0 + c4*4];
      const float4 wb = *(const float4*)&W4l[(32+i)*68 + c0 + c4*4];
      t1[c4*4+0]=fmaf(v,wa.x,t1[c4*4+0]); t1[c4*4+1]=fmaf(v,wa.y,t1[c4*4+1]);
      t1[c4*4+2]=fmaf(v,wa.z,t1[c4*4+2]); t1[c4*4+3]=fmaf(v,wa.w,t1[c4*4+3]);
      qv[c4*4+0]=fmaf(v,wb.x,qv[c4*4+0]); qv[c4*4+1]=fmaf(v,wb.y,qv[c4*4+1]);
      qv[c4*4+2]=fmaf(v,wb.z,qv[c4*4+2]); qv[c4*4+3]=fmaf(v,wb.w,qv[c4*4+3]);
    }
  }
  float pv[32];
  #pragma unroll
  for (int c = 0; c < 32; ++c){
    pv[c] = t1[c] - qv[c] + B4[c0+c];
    Qp4[p*68 + c0 + c] = qv[c];
  }
  __syncthreads();
  const uchar* mi = (const uchar*)idxl + p*20;
  float Qs[32], Q2[32];
  #pragma unroll
  for (int c = 0; c < 32; ++c){ Qs[c]=0.f; Q2[c]=0.f; }
  #pragma unroll 1
  for (int k = 0; k < KK; ++k){
    const int j = (int)mi[k] * 68;
    #pragma unroll
    for (int c4 = 0; c4 < 8; ++c4){
      const float4 q = *(const float4*)&Qp4[j + c0 + c4*4];
      Qs[c4*4+0]+=q.x; Q2[c4*4+0]=fmaf(q.x,q.x,Q2[c4*4+0]);
      Qs[c4*4+1]+=q.y; Q2[c4*4+1]=fmaf(q.y,q.y,Q2[c4*4+1]);
      Qs[c4*4+2]+=q.z; Q2[c4*4+2]=fmaf(q.z,q.z,Q2[c4*4+2]);
      Qs[c4*4+3]+=q.w; Q2[c4*4+3]=fmaf(q.w,q.w,Q2[c4*4+3]);
    }
  }
  #pragma unroll
  for (int c = 0; c < 32; ++c){
    float a = fmaf(20.f, pv[c], Qs[c]);
    float q = fmaf(20.f*pv[c], pv[c], fmaf(2.f*pv[c], Qs[c], Q2[c]));
    #pragma unroll
    for (int m = 32; m; m >>= 1){ a += __shfl_xor(a,m,64); q += __shfl_xor(q,m,64); }
    if ((t & 63) == 0){ atomicAdd(&ssum[c0+c], a); atomicAdd(&ssq[c0+c], q); }
  }
  __syncthreads();
  if (t < 64){
    unsafeAtomicAdd(&stat[t], (double)ssum[t]);
    unsafeAtomicAdd(&stat[64+t], (double)ssq[t]);
  }
}

// ---------------- EC2 output: fully LDS-staged, QW buffer = W4l -> Qp4 -> W5l ----------------
__global__ __launch_bounds__(256) void ec2_m(const float* __restrict__ x1,
    const uchar* __restrict__ idx, const float* __restrict__ W4, const float* __restrict__ B4,
    const double* __restrict__ st4, const float* __restrict__ g4, const float* __restrict__ be4,
    const float* __restrict__ W5, const float* __restrict__ B5,
    float* __restrict__ x2){
  const int t = threadIdx.x, b = blockIdx.x;
  __shared__ float xm[128*68];   // X (stride 36) then mlds (stride 68)
  __shared__ float QW[128*68];   // W4l (stride 68) -> Qp4 -> W5l
  __shared__ float sc4l[64], sh4l[64];
  __shared__ uint idxl[640];
  if (t < 64) bn_make(st4, 64, g4, be4, sc4l, sh4l, t);
  const float* xb = x1 + (size_t)b*4096;
  for (int i4 = t; i4 < 1024; i4 += 256){
    const float4 v = *(const float4*)&xb[i4*4];
    *(float4*)&xm[(i4>>3)*36 + (i4&7)*4] = v;
  }
  for (int i4 = t; i4 < 1024; i4 += 256){
    const float4 v = *(const float4*)&W4[i4*4];
    *(float4*)&QW[(i4>>4)*68 + (i4&15)*4] = v;
  }
  const uint* ig = (const uint*)(idx + (size_t)b*2560);
  for (int i = t; i < 640; i += 256) idxl[i] = ig[i];
  __syncthreads();
  const int p = t & 127;
  const int c0 = __builtin_amdgcn_readfirstlane((t>>7)*32);
  float pv[32], qs[32];
  {
    float t1[32], qv[32];
    #pragma unroll
    for (int c = 0; c < 32; ++c){ t1[c]=0.f; qv[c]=0.f; }
    #pragma unroll 4
    for (int i = 0; i < 32; ++i){
      const float v = xm[p*36 + i];
      #pragma unroll
      for (int c4 = 0; c4 < 8; ++c4){
        const float4 wa = *(const float4*)&QW[i*68 + c0 + c4*4];
        const float4 wb = *(const float4*)&QW[(32+i)*68 + c0 + c4*4];
        t1[c4*4+0]=fmaf(v,wa.x,t1[c4*4+0]); t1[c4*4+1]=fmaf(v,wa.y,t1[c4*4+1]);
        t1[c4*4+2]=fmaf(v,wa.z,t1[c4*4+2]); t1[c4*4+3]=fmaf(v,wa.w,t1[c4*4+3]);
        qv[c4*4+0]=fmaf(v,wb.x,qv[c4*4+0]); qv[c4*4+1]=fmaf(v,wb.y,qv[c4*4+1]);
        qv[c4*4+2]=fmaf(v,wb.z,qv[c4*4+2]); qv[c4*4+3]=fmaf(v,wb.w,qv[c4*4+3]);
      }
    }
    #pragma unroll
    for (int c = 0; c < 32; ++c){
      const float sc = sc4l[c0+c];
      pv[c] = fmaf(t1[c] - qv[c] + B4[c0+c], sc, sh4l[c0+c]);
      qs[c] = qv[c]*sc;
    }
  }
  __syncthreads();   // all W4l reads done
  {
    const int sw = p & 7;
    #pragma unroll
    for (int cg = 0; cg < 8; ++cg){
      const int scg = cg ^ sw;
      *(float4*)&QW[p*68 + c0 + (scg<<2)] =
        make_float4(qs[cg*4], qs[cg*4+1], qs[cg*4+2], qs[cg*4+3]);
    }
  }
  __syncthreads();
  float macc[32];
  #pragma unroll
  for (int c = 0; c < 32; ++c) macc[c] = 0.f;
  const uchar* mi = (const uchar*)idxl + p*20;
  #pragma unroll 1
  for (int k = 0; k < KK; ++k){
    const int j = mi[k];
    const int jb = j*68 + c0, jsw = j & 7;
    #pragma unroll
    for (int c4 = 0; c4 < 8; ++c4){
      const float4 q = *(const float4*)&QW[jb + ((c4 ^ jsw)<<2)];
      macc[c4*4+0] += fmaxf(pv[c4*4+0] + q.x, 0.f);
      macc[c4*4+1] += fmaxf(pv[c4*4+1] + q.y, 0.f);
      macc[c4*4+2] += fmaxf(pv[c4*4+2] + q.z, 0.f);
      macc[c4*4+3] += fmaxf(pv[c4*4+3] + q.w, 0.f);
    }
  }
  #pragma unroll
  for (int c4 = 0; c4 < 8; ++c4)
    *(float4*)&xm[p*68 + c0 + c4*4] =
      make_float4(macc[c4*4]*INVK, macc[c4*4+1]*INVK, macc[c4*4+2]*INVK, macc[c4*4+3]*INVK);
  __syncthreads();   // all Qp4 reads done
  for (int i4 = t; i4 < 1024; i4 += 256){
    const float4 v = *(const float4*)&W5[i4*4];
    *(float4*)&QW[(i4>>4)*68 + (i4&15)*4] = v;
  }
  __syncthreads();
  float o[32];
  #pragma unroll
  for (int c = 0; c < 32; ++c) o[c] = B5[c0 + c];
  #pragma unroll 4
  for (int i = 0; i < 64; ++i){
    const float v = xm[p*68 + i];
    #pragma unroll
    for (int c4 = 0; c4 < 8; ++c4){
      const float4 w = *(const float4*)&QW[i*68 + c0 + c4*4];
      o[c4*4+0]=fmaf(v,w.x,o[c4*4+0]); o[c4*4+1]=fmaf(v,w.y,o[c4*4+1]);
      o[c4*4+2]=fmaf(v,w.z,o[c4*4+2]); o[c4*4+3]=fmaf(v,w.w,o[c4*4+3]);
    }
  }
  float* ox = x2 + ((size_t)b*128 + p)*64 + c0;
  #pragma unroll
  for (int c4 = 0; c4 < 8; ++c4)
    *(float4*)&ox[c4*4] = make_float4(o[c4*4], o[c4*4+1], o[c4*4+2], o[c4*4+3]);
}

// ---------------- global max over N + head MLP ----------------
__global__ __launch_bounds__(128) void head_kernel(const float* __restrict__ x2,
    const float* __restrict__ w1, const float* __restrict__ b1,
    const float* __restrict__ w2, const float* __restrict__ b2,
    const float* __restrict__ w3, const float* __restrict__ b3,
    float* __restrict__ out){
  const int b = blockIdx.x, t = threadIdx.x;
  __shared__ float gmax2[128];
  __shared__ float h1s[128];
  __shared__ float part[2];
  {
    const int c = t & 63, nh = t >> 6;
    const float* xb = x2 + (size_t)b * 128 * 64 + (size_t)nh * 64 * 64 + c;
    float m = -3.0e38f;
    for (int n = 0; n < 64; ++n) m = fmaxf(m, xb[n*64]);
    gmax2[t] = m;
  }
  __syncthreads();
  float a = b1[t];
  #pragma unroll
  for (int i = 0; i < 64; ++i) a = fmaf(fmaxf(gmax2[i], gmax2[64+i]), w1[i*128 + t], a);
  h1s[t] = fmaxf(a, 0.f);
  __syncthreads();
  float h2 = b2[t];
  #pragma unroll
  for (int i = 0; i < 128; ++i) h2 = fmaf(h1s[i], w2[i*128 + t], h2);
  h2 = fmaxf(h2, 0.f);
  float pr = h2 * w3[t];
  #pragma unroll
  for (int m = 32; m; m >>= 1) pr += __shfl_xor(pr, m, 64);
  if ((t & 63) == 0) part[t >> 6] = pr;
  __syncthreads();
  if (t == 0) out[b] = part[0] + part[1] + b3[0];
}

extern "C" void kernel_launch(void* const* d_in, const int* in_sizes, int n_in,
                              void* d_out, int out_size, void* d_ws, size_t ws_size,
                              hipStream_t stream) {
  const float* points = (const float*)d_in[0];
  const float* feat   = (const float*)d_in[1];
  const float* c1_w1  = (const float*)d_in[2];
  const float* c1_b1  = (const float*)d_in[3];
  const float* c1_g1  = (const float*)d_in[4];
  const float* c1_be1 = (const float*)d_in[5];
  const float* c1_w2  = (const float*)d_in[6];
  const float* c1_b2  = (const float*)d_in[7];
  const float* c1_g2  = (const float*)d_in[8];
  const float* c1_be2 = (const float*)d_in[9];
  const float* c1_w3  = (const float*)d_in[10];
  const float* c1_b3  = (const float*)d_in[11];
  const float* c2_w1  = (const float*)d_in[12];
  const float* c2_b1  = (const float*)d_in[13];
  const float* c2_g1  = (const float*)d_in[14];
  const float* c2_be1 = (const float*)d_in[15];
  const float* c2_w2  = (const float*)d_in[16];
  const float* c2_b2  = (const float*)d_in[17];
  const float* m_w1   = (const float*)d_in[18];
  const float* m_b1   = (const float*)d_in[19];
  const float* m_w2   = (const float*)d_in[20];
  const float* m_b2   = (const float*)d_in[21];
  const float* m_w3   = (const float*)d_in[22];
  const float* m_b3   = (const float*)d_in[23];
  float* out = (float*)d_out;

  char* ws = (char*)d_ws;
  const size_t NEDGE = (size_t)512 * 128 * KK;
  uchar*  idx1 = (uchar*)ws;
  uchar*  idx2 = (uchar*)(ws + NEDGE);
  float*  x1   = (float*)(ws + 2*NEDGE);                       // 8.39 MB
  float*  x2   = (float*)(ws + 2*NEDGE + (size_t)65536*32*4);  // 16.8 MB
  double* stats = (double*)(ws + 2*NEDGE + (size_t)65536*96*4);
  double* st1 = stats;         // [sum32 | sq32]  (h1)
  double* st2 = stats + 64;    // [sum32 | sq32]  (h2)
  double* st4 = stats + 128;   // [sum64 | sq64]  (h4)

  hipMemsetAsync(stats, 0, 256*sizeof(double), stream);

  knn1_kernel<<<512, 256, 0, stream>>>(points, idx1);
  pqs1      <<<512, 256, 0, stream>>>(feat, idx1, c1_w1, c1_b1, st1);
  ec1_s2    <<<512, 512, 0, stream>>>(feat, idx1, c1_w1, c1_b1, st1, c1_g1, c1_be1,
                                      c1_w2, c1_b2, st2);
  ec1_m     <<<512, 512, 0, stream>>>(feat, idx1, c1_w1, c1_b1, st1, c1_g1, c1_be1,
                                      c1_w2, c1_b2, st2, c1_g2, c1_be2, c1_w3, c1_b3, x1);
  knn2_kernel<<<512, 256, 0, stream>>>(x1, idx2);
  pqs4      <<<512, 256, 0, stream>>>(x1, idx2, c2_w1, c2_b1, st4);
  ec2_m     <<<512, 256, 0, stream>>>(x1, idx2, c2_w1, c2_b1, st4, c2_g1, c2_be1,
                                      c2_w2, c2_b2, x2);
  head_kernel<<<512, 128, 0, stream>>>(x2, m_w1, m_b1, m_w2, m_b2, m_w3, m_b3, out);
}